// Round 6
// baseline (494.058 us; speedup 1.0000x reference)
//
#include <hip/hip_runtime.h>

// LSA fused attention: out = softmax(QK^T/temp, diag=-inf) @ V
// B=64, N=1024, D=768, fp32 I/O, bf16 MFMA 32x32x16.
//
// One merged prepass kernel rewrites Q(scaled),K,V as MFMA-fragment-ordered
// bf16 images in d_ws. Main kernel: BKV=512 per tile, 64 kv per wave
// (2 K-frags x 2 Q-frags -> 4 MFMA per step: halves Q-LDS bytes/MFMA).
// K/V frags global->VGPR (coalesced base+lane*16, each byte read once per
// block) with rings (K:4/slot, V:2) + lgkm-only barriers so prefetches
// survive; P exchanged via LDS in two 32KB sub-phases. Q resident in LDS.

typedef __bf16 bf16x8 __attribute__((ext_vector_type(8)));
typedef __bf16 bf16x4 __attribute__((ext_vector_type(4)));
typedef float  f32x16 __attribute__((ext_vector_type(16)));
typedef float  f32x4v __attribute__((ext_vector_type(4)));

#define WS_Q 0UL
#define WS_K 100663296UL
#define WS_V 201326592UL
#define WS_NEEDED 301989888UL

#define QOFF   0          // 96 KB Q frag image (resident; reused as O-transpose)
#define POFF   98304      // 32 KB P frag blocks (one PV sub-phase)
#define REDOFF 131072     // redm 2KB + redl 2KB
#define LDS_MAIN 135168

__device__ __forceinline__ void gld16(const void* g, const char* l) {
    __builtin_amdgcn_global_load_lds(
        (const __attribute__((address_space(1))) unsigned int*)g,
        (__attribute__((address_space(3))) unsigned int*)(l), 16, 0, 0);
}

#define LGKM0_BAR() do {                                            \
    asm volatile("s_waitcnt lgkmcnt(0)" ::: "memory");              \
    __builtin_amdgcn_s_barrier();                                   \
    asm volatile("" ::: "memory"); } while (0)

// ============================ merged prepass ============================
// grid 2048 x 512 thr: bid<1024 -> Q tile (b*16+qt); <1536 -> K (b*8+t); else V.
__global__ __launch_bounds__(512) void prep_all(
    const float* __restrict__ Qg, const float* __restrict__ Kg,
    const float* __restrict__ Vg, const float* __restrict__ Tg,
    unsigned short* __restrict__ Qws, unsigned short* __restrict__ Kws,
    unsigned short* __restrict__ Vws)
{
    __shared__ __align__(16) char Lraw[34816];
    const int bid = blockIdx.x;
    const int tid = threadIdx.x;

    if (bid < 1024) {
        // ---- Q: 64x768, scaled, -> frag image ----
        const float scale2 = 1.4426950408889634f / Tg[0];   // log2(e)/temp
        const float* src = Qg + (size_t)bid * 49152;
        char* outb = (char*)Qws + (size_t)bid * 98304;
        const int row = tid >> 3;
        const int c0  = tid & 7;            // 8 cols of 8 floats
        #pragma unroll 1
        for (int st = 0; st < 12; ++st) {
            #pragma unroll
            for (int i = 0; i < 2; ++i) {
                f32x4v v = *(const f32x4v*)(src + (size_t)row * 768 + st * 64 + c0 * 8 + i * 4);
                bf16x4 hb = { (__bf16)(v[0] * scale2), (__bf16)(v[1] * scale2),
                              (__bf16)(v[2] * scale2), (__bf16)(v[3] * scale2) };
                *(bf16x4*)(Lraw + row * 144 + (c0 * 8 + i * 4) * 2) = hb;
            }
            __syncthreads();
            {
                int u = tid;                               // [0,512)
                int ks = u >> 7, mrr = (u >> 6) & 1, l = u & 63;
                bf16x8 f = *(const bf16x8*)(Lraw + (mrr * 32 + (l & 31)) * 144
                                            + ks * 32 + 16 * (l >> 5));
                *(bf16x8*)(outb + (size_t)st * 8192 + u * 16) = f;
            }
            __syncthreads();
        }
    } else if (bid < 1536) {
        // ---- K: 128x768 -> frag image ----
        const int b2 = bid - 1024;
        const float* src = Kg + (size_t)b2 * 98304;
        char* outb = (char*)Kws + (size_t)b2 * 196608;
        const int kv = tid >> 2;
        const int k0 = (tid & 3) * 16;
        #pragma unroll 1
        for (int st = 0; st < 12; ++st) {
            #pragma unroll
            for (int i = 0; i < 4; ++i) {
                f32x4v v = *(const f32x4v*)(src + (size_t)kv * 768 + st * 64 + k0 + i * 4);
                bf16x4 hb = { (__bf16)v[0], (__bf16)v[1], (__bf16)v[2], (__bf16)v[3] };
                *(bf16x4*)(Lraw + kv * 144 + (k0 + i * 4) * 2) = hb;
            }
            __syncthreads();
            #pragma unroll
            for (int i = 0; i < 2; ++i) {
                int u = tid * 2 + i;                       // [0,1024)
                int ks = u >> 8, ncc = (u >> 6) & 3, l = u & 63;
                bf16x8 f = *(const bf16x8*)(Lraw + (ncc * 32 + (l & 31)) * 144
                                            + ks * 32 + 16 * (l >> 5));
                *(bf16x8*)(outb + (size_t)st * 16384 + u * 16) = f;
            }
            __syncthreads();
        }
    } else {
        // ---- V: 128x768 -> transposed frag image ----
        const int b2 = bid - 1536;
        const float* src = Vg + (size_t)b2 * 98304;
        char* outb = (char*)Vws + (size_t)b2 * 196608;
        const int srg = tid & 31, scg = tid >> 5;
        #pragma unroll 1
        for (int jg = 0; jg < 6; ++jg) {
            #pragma unroll
            for (int i2 = 0; i2 < 2; ++i2) {
                int cg = scg + i2 * 16;
                const float* vp = src + (size_t)(srg * 4) * 768 + jg * 128 + cg * 4;
                f32x4v a0 = *(const f32x4v*)(vp);
                f32x4v a1 = *(const f32x4v*)(vp + 768);
                f32x4v a2 = *(const f32x4v*)(vp + 1536);
                f32x4v a3 = *(const f32x4v*)(vp + 2304);
                #pragma unroll
                for (int c = 0; c < 4; ++c) {
                    int d = cg * 4 + c;
                    bf16x4 hb = { (__bf16)a0[c], (__bf16)a1[c], (__bf16)a2[c], (__bf16)a3[c] };
                    *(bf16x4*)(Lraw + d * 272 + srg * 8) = hb;
                }
            }
            __syncthreads();
            #pragma unroll
            for (int i = 0; i < 4; ++i) {
                int u = tid * 4 + i;                       // [0,2048)
                int kh = u >> 10, ks = (u >> 8) & 3, ncc = (u >> 6) & 3, l = u & 63;
                bf16x8 f = *(const bf16x8*)(Lraw + (ncc * 32 + (l & 31)) * 272
                                            + kh * 128 + ks * 32 + 16 * (l >> 5));
                *(bf16x8*)(outb + (size_t)(jg * 2 + kh) * 16384 + (u & 1023) * 16) = f;
            }
            __syncthreads();
        }
    }
}

// ============================ main kernel ============================
// Per block: 64 q rows, 8 waves. BKV=512 (t2 in {0,1}).
// Wave w: kv rows [w*64, w*64+64) = 2 kv-slots (kk) of 32; q = 2 groups (qg).
// K frag (t2, step st 0..47, kk): kimg + t2*786432 + (w>>1)*196608
//   + (w&1)*2048 + OFFK(st) + kk*1024 + lane*16
// V frag (t2, lksl 0..31, g3): vimg + t2*786432 + OFFV(lksl) + voff3[g3]
#define OFFK(st)  ((size_t)((st) >> 2) * 16384 + (size_t)((st) & 3) * 4096)
#define OFFV(ks)  ((size_t)((ks) >> 3) * 196608 + (size_t)(((ks) >> 2) & 1) * 16384 \
                   + (size_t)((ks) & 3) * 4096)

__global__ __launch_bounds__(512, 2) void lsa_main(
    const unsigned short* __restrict__ Qws, const unsigned short* __restrict__ Kws,
    const unsigned short* __restrict__ Vws, float* __restrict__ Og)
{
    extern __shared__ char sm[];
    const int tid  = threadIdx.x;
    const int lane = tid & 63;
    const int w    = tid >> 6;
    const int hh   = lane >> 5;
    const int l31  = lane & 31;

    int id = blockIdx.x;
    int xcd = id & 7, jj = id >> 3;
    int batch = (jj >> 5) * 16 + xcd * 2 + ((jj >> 4) & 1);
    int qt = jj & 15;

    const char* qimg = (const char*)Qws + (size_t)(batch * 16 + qt) * 98304;
    const char* kimg = (const char*)Kws + (size_t)batch * 1572864;
    const char* vimg = (const char*)Vws + (size_t)batch * 1572864;
    float* redm = (float*)(sm + REDOFF);
    float* redl = (float*)(sm + REDOFF + 2048);

    // ---- stage Q image (96 KB) into LDS ----
    #pragma unroll
    for (int i = 0; i < 12; ++i)
        gld16(qimg + i * 8192 + tid * 16, sm + QOFF + i * 8192 + w * 1024);
    __syncthreads();

    f32x16 acc[3][2];
    #pragma unroll
    for (int g3 = 0; g3 < 3; ++g3)
        #pragma unroll
        for (int qg = 0; qg < 2; ++qg)
            #pragma unroll
            for (int r = 0; r < 16; ++r) acc[g3][qg][r] = 0.0f;
    float m_st[2] = { -3e38f, -3e38f };
    float l_st[2] = { 0.0f, 0.0f };

    const char* kbase = kimg + (size_t)(w >> 1) * 196608 + (size_t)(w & 1) * 2048
                        + (size_t)lane * 16;
    size_t voff3[3];
    #pragma unroll
    for (int g3 = 0; g3 < 3; ++g3) {
        int dgi = w * 3 + g3;
        voff3[g3] = (size_t)(dgi >> 2) * 32768 + (size_t)(dgi & 3) * 1024
                    + (size_t)lane * 16;
    }
    const int diag_t2 = qt >> 3;
    const int wlo = (w < 4);

    #pragma unroll 1
    for (int t2 = 0; t2 < 2; ++t2) {
        // ================= QK^T: 48 steps x 4 MFMA =================
        const char* kb = kbase + (size_t)t2 * 786432;
        f32x16 s[2][2];
        #pragma unroll
        for (int kk = 0; kk < 2; ++kk)
            #pragma unroll
            for (int qg = 0; qg < 2; ++qg)
                #pragma unroll
                for (int r = 0; r < 16; ++r) s[kk][qg][r] = 0.0f;

        bf16x8 kr[2][4];
        #pragma unroll
        for (int p = 0; p < 4; ++p) {
            kr[0][p] = *(const bf16x8*)(kb + OFFK(p));
            kr[1][p] = *(const bf16x8*)(kb + OFFK(p) + 1024);
        }

        #pragma unroll
        for (int st = 0; st < 48; ++st) {
            bf16x8 qf0 = *(const bf16x8*)(sm + QOFF + (st * 2 + 0) * 1024 + lane * 16);
            bf16x8 qf1 = *(const bf16x8*)(sm + QOFF + (st * 2 + 1) * 1024 + lane * 16);
            __builtin_amdgcn_s_setprio(1);
            s[0][0] = __builtin_amdgcn_mfma_f32_32x32x16_bf16(kr[0][st & 3], qf0, s[0][0], 0, 0, 0);
            s[0][1] = __builtin_amdgcn_mfma_f32_32x32x16_bf16(kr[0][st & 3], qf1, s[0][1], 0, 0, 0);
            s[1][0] = __builtin_amdgcn_mfma_f32_32x32x16_bf16(kr[1][st & 3], qf0, s[1][0], 0, 0, 0);
            s[1][1] = __builtin_amdgcn_mfma_f32_32x32x16_bf16(kr[1][st & 3], qf1, s[1][1], 0, 0, 0);
            __builtin_amdgcn_s_setprio(0);
            if (st < 44) {
                kr[0][st & 3] = *(const bf16x8*)(kb + OFFK(st + 4));
                kr[1][st & 3] = *(const bf16x8*)(kb + OFFK(st + 4) + 1024);
            }
        }

        // ---- V ring warm-up (lands under softmax) ----
        const char* vbt = vimg + (size_t)t2 * 786432;
        bf16x8 vrg[2][3];
        #pragma unroll
        for (int p = 0; p < 2; ++p)
            #pragma unroll
            for (int g3 = 0; g3 < 3; ++g3)
                vrg[p][g3] = *(const bf16x8*)(vbt + voff3[g3] + OFFV(p));

        // diagonal self-exclusion
        if (t2 == diag_t2) {
            #pragma unroll
            for (int kk = 0; kk < 2; ++kk)
                #pragma unroll
                for (int qg = 0; qg < 2; ++qg)
                    #pragma unroll
                    for (int r = 0; r < 16; ++r) {
                        int kvg = t2 * 512 + w * 64 + kk * 32 + (r & 3) + 8 * (r >> 2) + 4 * hh;
                        if (kvg == qt * 64 + qg * 32 + l31) s[kk][qg][r] = -3e38f;
                    }
        }

        // ================= online softmax =================
        #pragma unroll
        for (int qg = 0; qg < 2; ++qg) {
            float pm = s[0][qg][0];
            #pragma unroll
            for (int r = 1; r < 16; ++r) pm = fmaxf(pm, s[0][qg][r]);
            #pragma unroll
            for (int r = 0; r < 16; ++r) pm = fmaxf(pm, s[1][qg][r]);
            pm = fmaxf(pm, __shfl_xor(pm, 32, 64));
            if (hh == 0) redm[(qg * 32 + l31) * 8 + w] = pm;
        }
        LGKM0_BAR();                           // bar1
        float cf[2];
        #pragma unroll
        for (int qg = 0; qg < 2; ++qg) {
            const float* rp = redm + (qg * 32 + l31) * 8;
            f32x4v a = *(const f32x4v*)rp;
            f32x4v b = *(const f32x4v*)(rp + 4);
            float mn = fmaxf(fmaxf(fmaxf(a[0], a[1]), fmaxf(a[2], a[3])),
                             fmaxf(fmaxf(b[0], b[1]), fmaxf(b[2], b[3])));
            mn = fmaxf(mn, m_st[qg]);
            cf[qg] = __builtin_amdgcn_exp2f(m_st[qg] - mn);
            m_st[qg] = mn;
            float pl = 0.0f;
            #pragma unroll
            for (int kk = 0; kk < 2; ++kk)
                #pragma unroll
                for (int r = 0; r < 16; ++r) {
                    float e = __builtin_amdgcn_exp2f(s[kk][qg][r] - mn);
                    s[kk][qg][r] = e; pl += e;
                }
            pl += __shfl_xor(pl, 32, 64);
            l_st[qg] = l_st[qg] * cf[qg] + pl;
        }
        #pragma unroll
        for (int g3 = 0; g3 < 3; ++g3)
            #pragma unroll
            for (int qg = 0; qg < 2; ++qg)
                #pragma unroll
                for (int r = 0; r < 16; ++r) acc[g3][qg][r] *= cf[qg];

        // P write helper pattern: wave w owns global ksl w*4+kk*2+(g>>1);
        // sub-phase uses local block ((w&3)*4+kk*2+(g>>1))*2+qg.
        #define WRITE_P() do {                                                      \
            _Pragma("unroll")                                                       \
            for (int kk = 0; kk < 2; ++kk)                                          \
                _Pragma("unroll")                                                   \
                for (int g = 0; g < 4; ++g)                                         \
                    _Pragma("unroll")                                               \
                    for (int qg = 0; qg < 2; ++qg) {                                \
                        bf16x4 p4 = { (__bf16)s[kk][qg][4*g+0], (__bf16)s[kk][qg][4*g+1], \
                                      (__bf16)s[kk][qg][4*g+2], (__bf16)s[kk][qg][4*g+3] }; \
                        int bidx = (((w & 3) * 4 + kk * 2 + (g >> 1)) * 2 + qg);    \
                        *(bf16x4*)(sm + POFF + bidx * 1024                          \
                                   + ((g & 1) * 32 + l31) * 16 + hh * 8) = p4;      \
                    } } while (0)

        if (wlo) WRITE_P();                    // waves 0-3: kv 0..255
        LGKM0_BAR();                           // bar2: P-A ready

        // ================= PV sub-phase A: lksl 0..15 =================
        #pragma unroll
        for (int lk = 0; lk < 16; ++lk) {
            bf16x8 pa0 = *(const bf16x8*)(sm + POFF + (lk * 2 + 0) * 1024 + lane * 16);
            bf16x8 pa1 = *(const bf16x8*)(sm + POFF + (lk * 2 + 1) * 1024 + lane * 16);
            __builtin_amdgcn_s_setprio(1);
            #pragma unroll
            for (int g3 = 0; g3 < 3; ++g3) {
                acc[g3][0] = __builtin_amdgcn_mfma_f32_32x32x16_bf16(vrg[lk & 1][g3], pa0, acc[g3][0], 0, 0, 0);
                acc[g3][1] = __builtin_amdgcn_mfma_f32_32x32x16_bf16(vrg[lk & 1][g3], pa1, acc[g3][1], 0, 0, 0);
            }
            __builtin_amdgcn_s_setprio(0);
            #pragma unroll
            for (int g3 = 0; g3 < 3; ++g3)
                vrg[lk & 1][g3] = *(const bf16x8*)(vbt + voff3[g3] + OFFV(lk + 2));
        }
        LGKM0_BAR();                           // bar3: P-A reads done
        if (!wlo) WRITE_P();                   // waves 4-7: kv 256..511
        LGKM0_BAR();                           // bar4: P-B ready

        // ================= PV sub-phase B: lksl 16..31 =================
        #pragma unroll
        for (int lk = 16; lk < 32; ++lk) {
            bf16x8 pa0 = *(const bf16x8*)(sm + POFF + ((lk - 16) * 2 + 0) * 1024 + lane * 16);
            bf16x8 pa1 = *(const bf16x8*)(sm + POFF + ((lk - 16) * 2 + 1) * 1024 + lane * 16);
            __builtin_amdgcn_s_setprio(1);
            #pragma unroll
            for (int g3 = 0; g3 < 3; ++g3) {
                acc[g3][0] = __builtin_amdgcn_mfma_f32_32x32x16_bf16(vrg[lk & 1][g3], pa0, acc[g3][0], 0, 0, 0);
                acc[g3][1] = __builtin_amdgcn_mfma_f32_32x32x16_bf16(vrg[lk & 1][g3], pa1, acc[g3][1], 0, 0, 0);
            }
            __builtin_amdgcn_s_setprio(0);
            if (lk < 30) {
                #pragma unroll
                for (int g3 = 0; g3 < 3; ++g3)
                    vrg[lk & 1][g3] = *(const bf16x8*)(vbt + voff3[g3] + OFFV(lk + 2));
            }
        }
        #undef WRITE_P
    }

    // ================= epilogue =================
    #pragma unroll
    for (int qg = 0; qg < 2; ++qg)
        if (hh == 0) redl[(qg * 32 + l31) * 8 + w] = l_st[qg];
    __syncthreads();
    float rinv[2];
    #pragma unroll
    for (int qg = 0; qg < 2; ++qg) {
        const float* rp = redl + (qg * 32 + l31) * 8;
        f32x4v a = *(const f32x4v*)rp;
        f32x4v b = *(const f32x4v*)(rp + 4);
        rinv[qg] = 1.0f / (a[0] + a[1] + a[2] + a[3] + b[0] + b[1] + b[2] + b[3]);
    }

    char* obt = sm + QOFF;                     // reuse Q space: [64 q][256 d] f32
    const size_t orow = (size_t)batch * 1024 + (size_t)qt * 64;
    const int q2 = tid >> 3, c8 = tid & 7;

    #pragma unroll
    for (int g3 = 0; g3 < 3; ++g3) {
        __syncthreads();
        #pragma unroll
        for (int qg = 0; qg < 2; ++qg) {
            int q = qg * 32 + l31;
            int qx = (q & 15) << 4;
            #pragma unroll
            for (int g = 0; g < 4; ++g) {
                f32x4v o4 = { acc[g3][qg][4 * g + 0] * rinv[qg],
                              acc[g3][qg][4 * g + 1] * rinv[qg],
                              acc[g3][qg][4 * g + 2] * rinv[qg],
                              acc[g3][qg][4 * g + 3] * rinv[qg] };
                int dloc = w * 32 + 8 * g + 4 * hh;
                *(f32x4v*)(obt + q * 1024 + ((dloc * 4) ^ qx)) = o4;
            }
        }
        __syncthreads();
        #pragma unroll
        for (int i = 0; i < 8; ++i) {
            int db = c8 * 128 + i * 16;
            f32x4v o = *(const f32x4v*)(obt + q2 * 1024 + (db ^ ((q2 & 15) << 4)));
            int dg = c8 * 96 + g3 * 32 + i * 4;
            *(f32x4v*)(Og + (orow + q2) * 768 + dg) = o;
        }
    }
}

// ============================ fallback (round-2 kernel) ============================
__device__ __forceinline__ void fb_stage_load(f32x4v (&vr)[2][4], const float* __restrict__ Vg,
                                              size_t kvbase, int srg, int scg, int ch) {
    #pragma unroll
    for (int i2 = 0; i2 < 2; ++i2) {
        const float* vp = Vg + kvbase + (size_t)(srg * 4) * 768 + ch * 128 + (scg + i2 * 16) * 4;
        #pragma unroll
        for (int rr = 0; rr < 4; ++rr)
            vr[i2][rr] = *(const f32x4v*)(vp + (size_t)rr * 768);
    }
}
__device__ __forceinline__ void fb_stage_write(const f32x4v (&vr)[2][4], char* Vb, int srg, int scg) {
    #pragma unroll
    for (int i2 = 0; i2 < 2; ++i2) {
        int cg = scg + i2 * 16;
        #pragma unroll
        for (int q4 = 0; q4 < 4; ++q4) {
            int drow = cg * 4 + q4;
            bf16x4 hv = { (__bf16)vr[i2][0][q4], (__bf16)vr[i2][1][q4],
                          (__bf16)vr[i2][2][q4], (__bf16)vr[i2][3][q4] };
            *(bf16x4*)(Vb + drow * 256 + ((srg * 8) ^ ((drow & 15) << 4))) = hv;
        }
    }
}
#define FB_OFF_V  98304
#define FB_OFF_P  131072
#define FB_OFF_RM 147456
#define FB_OFF_RL 148480
#define FB_LDS    149504
__global__ __launch_bounds__(512) void lsa_fb(
    const float* __restrict__ Qg, const float* __restrict__ Kg,
    const float* __restrict__ Vg, const float* __restrict__ Tg,
    float* __restrict__ Og)
{
    extern __shared__ char smem[];
    char*  Qb    = smem;
    char*  Vb    = smem + FB_OFF_V;
    char*  Pb    = smem + FB_OFF_P;
    float* red_m = (float*)(smem + FB_OFF_RM);
    float* red_l = (float*)(smem + FB_OFF_RL);
    const int tid  = threadIdx.x;
    const int lane = tid & 63;
    const int w    = tid >> 6;
    const int mr   = w & 1;
    const int nc   = w >> 1;
    const int half = lane >> 5;
    const int l31  = lane & 31;
    int id = blockIdx.x, xcd = id & 7, jj = id >> 3;
    int batch = (jj >> 5) * 16 + xcd * 2 + ((jj >> 4) & 1);
    int qt = jj & 15;
    const float scale2 = 1.4426950408889634f / Tg[0];
    {
        const float* qp   = Qg + ((size_t)batch * 1024 + (size_t)qt * 64) * 768;
        int   row   = tid >> 3, c0 = tid & 7;
        const float* qrow = qp + (size_t)row * 768;
        char* qdst  = Qb + row * 1536;
        int   rx    = (row & 15) << 4;
        #pragma unroll
        for (int j = 0; j < 24; ++j) {
            int c4 = c0 + j * 8;
            f32x4v q4 = *(const f32x4v*)(qrow + c4 * 4);
            bf16x4 hq = { (__bf16)(q4[0] * scale2), (__bf16)(q4[1] * scale2),
                          (__bf16)(q4[2] * scale2), (__bf16)(q4[3] * scale2) };
            *(bf16x4*)(qdst + ((c4 * 8) ^ rx)) = hq;
        }
    }
    __syncthreads();
    f32x16 acc[6];
    #pragma unroll
    for (int ch = 0; ch < 6; ++ch)
        #pragma unroll
        for (int r = 0; r < 16; ++r) acc[ch][r] = 0.0f;
    float m_st = -3e38f, l_st = 0.0f;
    const int  qrow_g = mr * 32 + l31;
    const int  qglob  = qt * 64 + qrow_g;
    char*      qfbase = Qb + qrow_g * 1536;
    const int  qx     = (qrow_g & 15) << 4;
    char*      pfbase = Pb + qrow_g * 256;
    const int  vrow   = nc * 32 + l31;
    char*      vfbase = Vb + vrow * 256;
    const int  vx     = (vrow & 15) << 4;
    const int  diag_tile = qt >> 1;
    const int  srg = tid & 31, scg = tid >> 5;
    #pragma unroll 1
    for (int t = 0; t < 8; ++t) {
        const size_t kvbase = ((size_t)batch * 1024 + (size_t)t * 128) * 768;
        f32x16 s;
        #pragma unroll
        for (int r = 0; r < 16; ++r) s[r] = 0.0f;
        const float* kptr = Kg + kvbase + (size_t)(nc * 32 + l31) * 768 + 8 * half;
        #pragma unroll
        for (int ch = 0; ch < 6; ++ch) {
            #pragma unroll
            for (int ks = 0; ks < 8; ++ks) {
                f32x4v k0 = *(const f32x4v*)(kptr + ch * 128 + ks * 16);
                f32x4v k1 = *(const f32x4v*)(kptr + ch * 128 + ks * 16 + 4);
                bf16x8 kf = { (__bf16)k0[0], (__bf16)k0[1], (__bf16)k0[2], (__bf16)k0[3],
                              (__bf16)k1[0], (__bf16)k1[1], (__bf16)k1[2], (__bf16)k1[3] };
                bf16x8 qf = *(const bf16x8*)(qfbase + ((ch * 256 + ks * 32 + half * 16) ^ qx));
                s = __builtin_amdgcn_mfma_f32_32x32x16_bf16(kf, qf, s, 0, 0, 0);
            }
        }
        if (t == diag_tile) {
            #pragma unroll
            for (int r = 0; r < 16; ++r) {
                int kvg = t * 128 + nc * 32 + (r & 3) + 8 * (r >> 2) + 4 * half;
                if (kvg == qglob) s[r] = -3e38f;
            }
        }
        f32x4v vr[2][4];
        fb_stage_load(vr, Vg, kvbase, srg, scg, 0);
        float pm = s[0];
        #pragma unroll
        for (int r = 1; r < 16; ++r) pm = fmaxf(pm, s[r]);
        pm = fmaxf(pm, __shfl_xor(pm, 32, 64));
        if (half == 0) red_m[qrow_g * 4 + nc] = pm;
        __syncthreads();
        f32x4v m4 = *(const f32x4v*)(red_m + qrow_g * 4);
        float mnew = fmaxf(fmaxf(m4[0], m4[1]), fmaxf(m4[2], m4[3]));
        mnew = fmaxf(mnew, m_st);
        float cf = __builtin_amdgcn_exp2f(m_st - mnew);
        m_st = mnew;
        float pl = 0.0f;
        #pragma unroll
        for (int r = 0; r < 16; ++r) {
            float e = __builtin_amdgcn_exp2f(s[r] - mnew);
            s[r] = e; pl += e;
        }
        pl += __shfl_xor(pl, 32, 64);
        l_st = l_st * cf + pl;
        #pragma unroll
        for (int ch = 0; ch < 6; ++ch)
            #pragma unroll
            for (int r = 0; r < 16; ++r) acc[ch][r] *= cf;
        #pragma unroll
        for (int g = 0; g < 4; ++g) {
            bf16x4 hp = { (__bf16)s[4*g+0], (__bf16)s[4*g+1],
                          (__bf16)s[4*g+2], (__bf16)s[4*g+3] };
            *(bf16x4*)(pfbase + ((nc * 64 + g * 16 + half * 8) ^ qx)) = hp;
        }
        fb_stage_write(vr, Vb, srg, scg);
        __syncthreads();
        bf16x8 pa[8];
        #pragma unroll
        for (int ks = 0; ks < 8; ++ks)
            pa[ks] = *(const bf16x8*)(pfbase + ((ks * 32 + half * 16) ^ qx));
        #pragma unroll
        for (int ch = 0; ch < 6; ++ch) {
            if (ch < 5) fb_stage_load(vr, Vg, kvbase, srg, scg, ch + 1);
            #pragma unroll
            for (int ks = 0; ks < 8; ++ks) {
                bf16x8 vf = *(const bf16x8*)(vfbase + ((ks * 32 + half * 16) ^ vx));
                acc[ch] = __builtin_amdgcn_mfma_f32_32x32x16_bf16(vf, pa[ks], acc[ch], 0, 0, 0);
            }
            if (ch < 5) {
                __syncthreads();
                fb_stage_write(vr, Vb, srg, scg);
                __syncthreads();
            }
        }
    }
    if (half == 0) red_l[qrow_g * 4 + nc] = l_st;
    __syncthreads();
    f32x4v l4 = *(const f32x4v*)(red_l + qrow_g * 4);
    float rinv = 1.0f / (l4[0] + l4[1] + l4[2] + l4[3]);
    float* op = Og + ((size_t)batch * 1024 + (size_t)qglob) * 768;
    #pragma unroll
    for (int ch = 0; ch < 6; ++ch)
        #pragma unroll
        for (int g = 0; g < 4; ++g) {
            f32x4v o4 = { acc[ch][4*g+0] * rinv, acc[ch][4*g+1] * rinv,
                          acc[ch][4*g+2] * rinv, acc[ch][4*g+3] * rinv };
            *(f32x4v*)(op + ch * 128 + nc * 32 + g * 8 + half * 4) = o4;
        }
}

extern "C" void kernel_launch(void* const* d_in, const int* in_sizes, int n_in,
                              void* d_out, int out_size, void* d_ws, size_t ws_size,
                              hipStream_t stream) {
    (void)in_sizes; (void)n_in; (void)out_size;
    const float* Q = (const float*)d_in[0];
    const float* K = (const float*)d_in[1];
    const float* V = (const float*)d_in[2];
    const float* T = (const float*)d_in[3];
    float* O = (float*)d_out;
    if (ws_size >= WS_NEEDED) {
        unsigned short* Qws = (unsigned short*)((char*)d_ws + WS_Q);
        unsigned short* Kws = (unsigned short*)((char*)d_ws + WS_K);
        unsigned short* Vws = (unsigned short*)((char*)d_ws + WS_V);
        prep_all<<<dim3(2048), dim3(512), 0, stream>>>(Q, K, V, T, Qws, Kws, Vws);
        lsa_main<<<dim3(1024), dim3(512), LDS_MAIN, stream>>>(Qws, Kws, Vws, O);
    } else {
        lsa_fb<<<dim3(1024), dim3(512), FB_LDS, stream>>>(Q, K, V, T, O);
    }
}

// Round 7
// 488.146 us; speedup vs baseline: 1.0121x; 1.0121x over previous
//
#include <hip/hip_runtime.h>

// LSA fused attention: out = softmax(QK^T/temp, diag=-inf) @ V
// B=64, N=1024, D=768, fp32 I/O, bf16 MFMA 32x32x16.
//
// Merged prepass rewrites Q(scaled),K,V as MFMA-fragment-ordered bf16 images
// in d_ws. Main kernel: BKV=512/tile, 64 kv per wave (2 K x 2 Q frags -> 4
// MFMA/step). K/V frags global->VGPR (each byte read once per block);
// K ring depth 5, V ring depth 2. NEW (R7): Q-frag and P-frag register
// double-buffers -- next step's ds_reads issue before current MFMAs, so
// LDS latency hides under the matrix pipe (2 waves/SIMD can't hide it via
// TLP). lgkm-only barriers keep global prefetches alive across sync.

typedef __bf16 bf16x8 __attribute__((ext_vector_type(8)));
typedef __bf16 bf16x4 __attribute__((ext_vector_type(4)));
typedef float  f32x16 __attribute__((ext_vector_type(16)));
typedef float  f32x4v __attribute__((ext_vector_type(4)));

#define WS_Q 0UL
#define WS_K 100663296UL
#define WS_V 201326592UL
#define WS_NEEDED 301989888UL

#define QOFF   0          // 96 KB Q frag image (resident; reused as O-transpose)
#define POFF   98304      // 32 KB P frag blocks (one PV sub-phase)
#define REDOFF 131072     // redm 2KB + redl 2KB
#define LDS_MAIN 135168

__device__ __forceinline__ void gld16(const void* g, const char* l) {
    __builtin_amdgcn_global_load_lds(
        (const __attribute__((address_space(1))) unsigned int*)g,
        (__attribute__((address_space(3))) unsigned int*)(l), 16, 0, 0);
}

#define LGKM0_BAR() do {                                            \
    asm volatile("s_waitcnt lgkmcnt(0)" ::: "memory");              \
    __builtin_amdgcn_s_barrier();                                   \
    asm volatile("" ::: "memory"); } while (0)

// ============================ merged prepass ============================
// grid 2048 x 512 thr: bid<1024 -> Q tile (b*16+qt); <1536 -> K (b*8+t); else V.
__global__ __launch_bounds__(512) void prep_all(
    const float* __restrict__ Qg, const float* __restrict__ Kg,
    const float* __restrict__ Vg, const float* __restrict__ Tg,
    unsigned short* __restrict__ Qws, unsigned short* __restrict__ Kws,
    unsigned short* __restrict__ Vws)
{
    __shared__ __align__(16) char Lraw[34816];
    const int bid = blockIdx.x;
    const int tid = threadIdx.x;

    if (bid < 1024) {
        // ---- Q: 64x768, scaled, -> frag image ----
        const float scale2 = 1.4426950408889634f / Tg[0];   // log2(e)/temp
        const float* src = Qg + (size_t)bid * 49152;
        char* outb = (char*)Qws + (size_t)bid * 98304;
        const int row = tid >> 3;
        const int c0  = tid & 7;            // 8 cols of 8 floats
        #pragma unroll 1
        for (int st = 0; st < 12; ++st) {
            #pragma unroll
            for (int i = 0; i < 2; ++i) {
                f32x4v v = *(const f32x4v*)(src + (size_t)row * 768 + st * 64 + c0 * 8 + i * 4);
                bf16x4 hb = { (__bf16)(v[0] * scale2), (__bf16)(v[1] * scale2),
                              (__bf16)(v[2] * scale2), (__bf16)(v[3] * scale2) };
                *(bf16x4*)(Lraw + row * 144 + (c0 * 8 + i * 4) * 2) = hb;
            }
            __syncthreads();
            {
                int u = tid;                               // [0,512)
                int ks = u >> 7, mrr = (u >> 6) & 1, l = u & 63;
                bf16x8 f = *(const bf16x8*)(Lraw + (mrr * 32 + (l & 31)) * 144
                                            + ks * 32 + 16 * (l >> 5));
                *(bf16x8*)(outb + (size_t)st * 8192 + u * 16) = f;
            }
            __syncthreads();
        }
    } else if (bid < 1536) {
        // ---- K: 128x768 -> frag image ----
        const int b2 = bid - 1024;
        const float* src = Kg + (size_t)b2 * 98304;
        char* outb = (char*)Kws + (size_t)b2 * 196608;
        const int kv = tid >> 2;
        const int k0 = (tid & 3) * 16;
        #pragma unroll 1
        for (int st = 0; st < 12; ++st) {
            #pragma unroll
            for (int i = 0; i < 4; ++i) {
                f32x4v v = *(const f32x4v*)(src + (size_t)kv * 768 + st * 64 + k0 + i * 4);
                bf16x4 hb = { (__bf16)v[0], (__bf16)v[1], (__bf16)v[2], (__bf16)v[3] };
                *(bf16x4*)(Lraw + kv * 144 + (k0 + i * 4) * 2) = hb;
            }
            __syncthreads();
            #pragma unroll
            for (int i = 0; i < 2; ++i) {
                int u = tid * 2 + i;                       // [0,1024)
                int ks = u >> 8, ncc = (u >> 6) & 3, l = u & 63;
                bf16x8 f = *(const bf16x8*)(Lraw + (ncc * 32 + (l & 31)) * 144
                                            + ks * 32 + 16 * (l >> 5));
                *(bf16x8*)(outb + (size_t)st * 16384 + u * 16) = f;
            }
            __syncthreads();
        }
    } else {
        // ---- V: 128x768 -> transposed frag image ----
        const int b2 = bid - 1536;
        const float* src = Vg + (size_t)b2 * 98304;
        char* outb = (char*)Vws + (size_t)b2 * 196608;
        const int srg = tid & 31, scg = tid >> 5;
        #pragma unroll 1
        for (int jg = 0; jg < 6; ++jg) {
            #pragma unroll
            for (int i2 = 0; i2 < 2; ++i2) {
                int cg = scg + i2 * 16;
                const float* vp = src + (size_t)(srg * 4) * 768 + jg * 128 + cg * 4;
                f32x4v a0 = *(const f32x4v*)(vp);
                f32x4v a1 = *(const f32x4v*)(vp + 768);
                f32x4v a2 = *(const f32x4v*)(vp + 1536);
                f32x4v a3 = *(const f32x4v*)(vp + 2304);
                #pragma unroll
                for (int c = 0; c < 4; ++c) {
                    int d = cg * 4 + c;
                    bf16x4 hb = { (__bf16)a0[c], (__bf16)a1[c], (__bf16)a2[c], (__bf16)a3[c] };
                    *(bf16x4*)(Lraw + d * 272 + srg * 8) = hb;
                }
            }
            __syncthreads();
            #pragma unroll
            for (int i = 0; i < 4; ++i) {
                int u = tid * 4 + i;                       // [0,2048)
                int kh = u >> 10, ks = (u >> 8) & 3, ncc = (u >> 6) & 3, l = u & 63;
                bf16x8 f = *(const bf16x8*)(Lraw + (ncc * 32 + (l & 31)) * 272
                                            + kh * 128 + ks * 32 + 16 * (l >> 5));
                *(bf16x8*)(outb + (size_t)(jg * 2 + kh) * 16384 + (u & 1023) * 16) = f;
            }
            __syncthreads();
        }
    }
}

// ============================ main kernel ============================
#define OFFK(st)  ((size_t)((st) >> 2) * 16384 + (size_t)((st) & 3) * 4096)
#define OFFV(ks)  ((size_t)((ks) >> 3) * 196608 + (size_t)(((ks) >> 2) & 1) * 16384 \
                   + (size_t)((ks) & 3) * 4096)

__global__ __launch_bounds__(512, 2) void lsa_main(
    const unsigned short* __restrict__ Qws, const unsigned short* __restrict__ Kws,
    const unsigned short* __restrict__ Vws, float* __restrict__ Og)
{
    extern __shared__ char sm[];
    const int tid  = threadIdx.x;
    const int lane = tid & 63;
    const int w    = tid >> 6;
    const int hh   = lane >> 5;
    const int l31  = lane & 31;

    int id = blockIdx.x;
    int xcd = id & 7, jj = id >> 3;
    int batch = (jj >> 5) * 16 + xcd * 2 + ((jj >> 4) & 1);
    int qt = jj & 15;

    const char* qimg = (const char*)Qws + (size_t)(batch * 16 + qt) * 98304;
    const char* kimg = (const char*)Kws + (size_t)batch * 1572864;
    const char* vimg = (const char*)Vws + (size_t)batch * 1572864;
    float* redm = (float*)(sm + REDOFF);
    float* redl = (float*)(sm + REDOFF + 2048);

    // ---- stage Q image (96 KB) into LDS ----
    #pragma unroll
    for (int i = 0; i < 12; ++i)
        gld16(qimg + i * 8192 + tid * 16, sm + QOFF + i * 8192 + w * 1024);
    __syncthreads();

    f32x16 acc[3][2];
    #pragma unroll
    for (int g3 = 0; g3 < 3; ++g3)
        #pragma unroll
        for (int qg = 0; qg < 2; ++qg)
            #pragma unroll
            for (int r = 0; r < 16; ++r) acc[g3][qg][r] = 0.0f;
    float m_st[2] = { -3e38f, -3e38f };
    float l_st[2] = { 0.0f, 0.0f };

    const char* kbase = kimg + (size_t)(w >> 1) * 196608 + (size_t)(w & 1) * 2048
                        + (size_t)lane * 16;
    size_t voff3[3];
    #pragma unroll
    for (int g3 = 0; g3 < 3; ++g3) {
        int dgi = w * 3 + g3;
        voff3[g3] = (size_t)(dgi >> 2) * 32768 + (size_t)(dgi & 3) * 1024
                    + (size_t)lane * 16;
    }
    const int diag_t2 = qt >> 3;
    const int wlo = (w < 4);

    #pragma unroll 1
    for (int t2 = 0; t2 < 2; ++t2) {
        // ================= QK^T: 48 steps x 4 MFMA, dbuf qf + ring-5 K =================
        const char* kb = kbase + (size_t)t2 * 786432;
        f32x16 s[2][2];
        #pragma unroll
        for (int kk = 0; kk < 2; ++kk)
            #pragma unroll
            for (int qg = 0; qg < 2; ++qg)
                #pragma unroll
                for (int r = 0; r < 16; ++r) s[kk][qg][r] = 0.0f;

        bf16x8 kr0[5], kr1[5];
        #pragma unroll
        for (int p = 0; p < 5; ++p) {
            kr0[p] = *(const bf16x8*)(kb + OFFK(p));
            kr1[p] = *(const bf16x8*)(kb + OFFK(p) + 1024);
        }
        bf16x8 qf[2][2];
        qf[0][0] = *(const bf16x8*)(sm + QOFF + 0 + lane * 16);
        qf[0][1] = *(const bf16x8*)(sm + QOFF + 1024 + lane * 16);

        #pragma unroll
        for (int st = 0; st < 48; ++st) {
            const int cur = st & 1, nxt = cur ^ 1;
            if (st < 47) {          // next step's Q frags: latency hides under MFMAs
                qf[nxt][0] = *(const bf16x8*)(sm + QOFF + ((st + 1) * 2 + 0) * 1024 + lane * 16);
                qf[nxt][1] = *(const bf16x8*)(sm + QOFF + ((st + 1) * 2 + 1) * 1024 + lane * 16);
            }
            __builtin_amdgcn_s_setprio(1);
            s[0][0] = __builtin_amdgcn_mfma_f32_32x32x16_bf16(kr0[st % 5], qf[cur][0], s[0][0], 0, 0, 0);
            s[0][1] = __builtin_amdgcn_mfma_f32_32x32x16_bf16(kr0[st % 5], qf[cur][1], s[0][1], 0, 0, 0);
            s[1][0] = __builtin_amdgcn_mfma_f32_32x32x16_bf16(kr1[st % 5], qf[cur][0], s[1][0], 0, 0, 0);
            s[1][1] = __builtin_amdgcn_mfma_f32_32x32x16_bf16(kr1[st % 5], qf[cur][1], s[1][1], 0, 0, 0);
            __builtin_amdgcn_s_setprio(0);
            if (st < 43) {          // ring refill, consumed 5 steps later
                kr0[st % 5] = *(const bf16x8*)(kb + OFFK(st + 5));
                kr1[st % 5] = *(const bf16x8*)(kb + OFFK(st + 5) + 1024);
            }
        }

        // ---- V ring warm-up (lands under softmax) ----
        const char* vbt = vimg + (size_t)t2 * 786432;
        bf16x8 vrg[2][3];
        #pragma unroll
        for (int p = 0; p < 2; ++p)
            #pragma unroll
            for (int g3 = 0; g3 < 3; ++g3)
                vrg[p][g3] = *(const bf16x8*)(vbt + voff3[g3] + OFFV(p));

        // diagonal self-exclusion
        if (t2 == diag_t2) {
            #pragma unroll
            for (int kk = 0; kk < 2; ++kk)
                #pragma unroll
                for (int qg = 0; qg < 2; ++qg)
                    #pragma unroll
                    for (int r = 0; r < 16; ++r) {
                        int kvg = t2 * 512 + w * 64 + kk * 32 + (r & 3) + 8 * (r >> 2) + 4 * hh;
                        if (kvg == qt * 64 + qg * 32 + l31) s[kk][qg][r] = -3e38f;
                    }
        }

        // ================= online softmax =================
        #pragma unroll
        for (int qg = 0; qg < 2; ++qg) {
            float pm = s[0][qg][0];
            #pragma unroll
            for (int r = 1; r < 16; ++r) pm = fmaxf(pm, s[0][qg][r]);
            #pragma unroll
            for (int r = 0; r < 16; ++r) pm = fmaxf(pm, s[1][qg][r]);
            pm = fmaxf(pm, __shfl_xor(pm, 32, 64));
            if (hh == 0) redm[(qg * 32 + l31) * 8 + w] = pm;
        }
        LGKM0_BAR();                           // bar1
        float cf[2];
        #pragma unroll
        for (int qg = 0; qg < 2; ++qg) {
            const float* rp = redm + (qg * 32 + l31) * 8;
            f32x4v a = *(const f32x4v*)rp;
            f32x4v b = *(const f32x4v*)(rp + 4);
            float mn = fmaxf(fmaxf(fmaxf(a[0], a[1]), fmaxf(a[2], a[3])),
                             fmaxf(fmaxf(b[0], b[1]), fmaxf(b[2], b[3])));
            mn = fmaxf(mn, m_st[qg]);
            cf[qg] = __builtin_amdgcn_exp2f(m_st[qg] - mn);
            m_st[qg] = mn;
            float pl = 0.0f;
            #pragma unroll
            for (int kk = 0; kk < 2; ++kk)
                #pragma unroll
                for (int r = 0; r < 16; ++r) {
                    float e = __builtin_amdgcn_exp2f(s[kk][qg][r] - mn);
                    s[kk][qg][r] = e; pl += e;
                }
            pl += __shfl_xor(pl, 32, 64);
            l_st[qg] = l_st[qg] * cf[qg] + pl;
        }

        // P write: wave w owns global ksl w*4+kk*2+(g>>1); local block in sub-phase.
        #define WRITE_P() do {                                                      \
            _Pragma("unroll")                                                       \
            for (int kk = 0; kk < 2; ++kk)                                          \
                _Pragma("unroll")                                                   \
                for (int g = 0; g < 4; ++g)                                         \
                    _Pragma("unroll")                                               \
                    for (int qg = 0; qg < 2; ++qg) {                                \
                        bf16x4 p4 = { (__bf16)s[kk][qg][4*g+0], (__bf16)s[kk][qg][4*g+1], \
                                      (__bf16)s[kk][qg][4*g+2], (__bf16)s[kk][qg][4*g+3] }; \
                        int bidx = (((w & 3) * 4 + kk * 2 + (g >> 1)) * 2 + qg);    \
                        *(bf16x4*)(sm + POFF + bidx * 1024                          \
                                   + ((g & 1) * 32 + l31) * 16 + hh * 8) = p4;      \
                    } } while (0)

        if (wlo) WRITE_P();                    // waves 0-3: kv 0..255

        // acc rescale AFTER P writes (independent VALU, overlaps ds_write/barrier)
        #pragma unroll
        for (int g3 = 0; g3 < 3; ++g3)
            #pragma unroll
            for (int qg = 0; qg < 2; ++qg)
                #pragma unroll
                for (int r = 0; r < 16; ++r) acc[g3][qg][r] *= cf[qg];

        LGKM0_BAR();                           // bar2: P-A ready

        // ================= PV sub-phase A: lk 0..15, dbuf pa + ring-2 V =================
        bf16x8 pa[2][2];
        pa[0][0] = *(const bf16x8*)(sm + POFF + 0 + lane * 16);
        pa[0][1] = *(const bf16x8*)(sm + POFF + 1024 + lane * 16);
        #pragma unroll
        for (int lk = 0; lk < 16; ++lk) {
            const int cur = lk & 1, nxt = cur ^ 1;
            if (lk < 15) {
                pa[nxt][0] = *(const bf16x8*)(sm + POFF + ((lk + 1) * 2 + 0) * 1024 + lane * 16);
                pa[nxt][1] = *(const bf16x8*)(sm + POFF + ((lk + 1) * 2 + 1) * 1024 + lane * 16);
            }
            __builtin_amdgcn_s_setprio(1);
            #pragma unroll
            for (int g3 = 0; g3 < 3; ++g3) {
                acc[g3][0] = __builtin_amdgcn_mfma_f32_32x32x16_bf16(vrg[lk & 1][g3], pa[cur][0], acc[g3][0], 0, 0, 0);
                acc[g3][1] = __builtin_amdgcn_mfma_f32_32x32x16_bf16(vrg[lk & 1][g3], pa[cur][1], acc[g3][1], 0, 0, 0);
            }
            __builtin_amdgcn_s_setprio(0);
            #pragma unroll
            for (int g3 = 0; g3 < 3; ++g3)
                vrg[lk & 1][g3] = *(const bf16x8*)(vbt + voff3[g3] + OFFV(lk + 2));
        }
        LGKM0_BAR();                           // bar3: P-A reads done
        if (!wlo) WRITE_P();                   // waves 4-7: kv 256..511
        LGKM0_BAR();                           // bar4: P-B ready

        // ================= PV sub-phase B: lk 16..31 =================
        pa[0][0] = *(const bf16x8*)(sm + POFF + 0 + lane * 16);
        pa[0][1] = *(const bf16x8*)(sm + POFF + 1024 + lane * 16);
        #pragma unroll
        for (int lk = 16; lk < 32; ++lk) {
            const int cur = lk & 1, nxt = cur ^ 1;
            if (lk < 31) {
                pa[nxt][0] = *(const bf16x8*)(sm + POFF + ((lk - 15) * 2 + 0) * 1024 + lane * 16);
                pa[nxt][1] = *(const bf16x8*)(sm + POFF + ((lk - 15) * 2 + 1) * 1024 + lane * 16);
            }
            __builtin_amdgcn_s_setprio(1);
            #pragma unroll
            for (int g3 = 0; g3 < 3; ++g3) {
                acc[g3][0] = __builtin_amdgcn_mfma_f32_32x32x16_bf16(vrg[lk & 1][g3], pa[cur][0], acc[g3][0], 0, 0, 0);
                acc[g3][1] = __builtin_amdgcn_mfma_f32_32x32x16_bf16(vrg[lk & 1][g3], pa[cur][1], acc[g3][1], 0, 0, 0);
            }
            __builtin_amdgcn_s_setprio(0);
            if (lk < 30) {
                #pragma unroll
                for (int g3 = 0; g3 < 3; ++g3)
                    vrg[lk & 1][g3] = *(const bf16x8*)(vbt + voff3[g3] + OFFV(lk + 2));
            }
        }
        #undef WRITE_P
    }

    // ================= epilogue =================
    #pragma unroll
    for (int qg = 0; qg < 2; ++qg)
        if (hh == 0) redl[(qg * 32 + l31) * 8 + w] = l_st[qg];
    __syncthreads();
    float rinv[2];
    #pragma unroll
    for (int qg = 0; qg < 2; ++qg) {
        const float* rp = redl + (qg * 32 + l31) * 8;
        f32x4v a = *(const f32x4v*)rp;
        f32x4v b = *(const f32x4v*)(rp + 4);
        rinv[qg] = 1.0f / (a[0] + a[1] + a[2] + a[3] + b[0] + b[1] + b[2] + b[3]);
    }

    char* obt = sm + QOFF;                     // reuse Q space: [64 q][256 d] f32
    const size_t orow = (size_t)batch * 1024 + (size_t)qt * 64;
    const int q2 = tid >> 3, c8 = tid & 7;

    #pragma unroll
    for (int g3 = 0; g3 < 3; ++g3) {
        __syncthreads();
        #pragma unroll
        for (int qg = 0; qg < 2; ++qg) {
            int q = qg * 32 + l31;
            int qx = (q & 15) << 4;
            #pragma unroll
            for (int g = 0; g < 4; ++g) {
                f32x4v o4 = { acc[g3][qg][4 * g + 0] * rinv[qg],
                              acc[g3][qg][4 * g + 1] * rinv[qg],
                              acc[g3][qg][4 * g + 2] * rinv[qg],
                              acc[g3][qg][4 * g + 3] * rinv[qg] };
                int dloc = w * 32 + 8 * g + 4 * hh;
                *(f32x4v*)(obt + q * 1024 + ((dloc * 4) ^ qx)) = o4;
            }
        }
        __syncthreads();
        #pragma unroll
        for (int i = 0; i < 8; ++i) {
            int db = c8 * 128 + i * 16;
            f32x4v o = *(const f32x4v*)(obt + q2 * 1024 + (db ^ ((q2 & 15) << 4)));
            int dg = c8 * 96 + g3 * 32 + i * 4;
            *(f32x4v*)(Og + (orow + q2) * 768 + dg) = o;
        }
    }
}

// ============================ fallback (round-2 kernel) ============================
__device__ __forceinline__ void fb_stage_load(f32x4v (&vr)[2][4], const float* __restrict__ Vg,
                                              size_t kvbase, int srg, int scg, int ch) {
    #pragma unroll
    for (int i2 = 0; i2 < 2; ++i2) {
        const float* vp = Vg + kvbase + (size_t)(srg * 4) * 768 + ch * 128 + (scg + i2 * 16) * 4;
        #pragma unroll
        for (int rr = 0; rr < 4; ++rr)
            vr[i2][rr] = *(const f32x4v*)(vp + (size_t)rr * 768);
    }
}
__device__ __forceinline__ void fb_stage_write(const f32x4v (&vr)[2][4], char* Vb, int srg, int scg) {
    #pragma unroll
    for (int i2 = 0; i2 < 2; ++i2) {
        int cg = scg + i2 * 16;
        #pragma unroll
        for (int q4 = 0; q4 < 4; ++q4) {
            int drow = cg * 4 + q4;
            bf16x4 hv = { (__bf16)vr[i2][0][q4], (__bf16)vr[i2][1][q4],
                          (__bf16)vr[i2][2][q4], (__bf16)vr[i2][3][q4] };
            *(bf16x4*)(Vb + drow * 256 + ((srg * 8) ^ ((drow & 15) << 4))) = hv;
        }
    }
}
#define FB_OFF_V  98304
#define FB_OFF_P  131072
#define FB_OFF_RM 147456
#define FB_OFF_RL 148480
#define FB_LDS    149504
__global__ __launch_bounds__(512) void lsa_fb(
    const float* __restrict__ Qg, const float* __restrict__ Kg,
    const float* __restrict__ Vg, const float* __restrict__ Tg,
    float* __restrict__ Og)
{
    extern __shared__ char smem[];
    char*  Qb    = smem;
    char*  Vb    = smem + FB_OFF_V;
    char*  Pb    = smem + FB_OFF_P;
    float* red_m = (float*)(smem + FB_OFF_RM);
    float* red_l = (float*)(smem + FB_OFF_RL);
    const int tid  = threadIdx.x;
    const int lane = tid & 63;
    const int w    = tid >> 6;
    const int mr   = w & 1;
    const int nc   = w >> 1;
    const int half = lane >> 5;
    const int l31  = lane & 31;
    int id = blockIdx.x, xcd = id & 7, jj = id >> 3;
    int batch = (jj >> 5) * 16 + xcd * 2 + ((jj >> 4) & 1);
    int qt = jj & 15;
    const float scale2 = 1.4426950408889634f / Tg[0];
    {
        const float* qp   = Qg + ((size_t)batch * 1024 + (size_t)qt * 64) * 768;
        int   row   = tid >> 3, c0 = tid & 7;
        const float* qrow = qp + (size_t)row * 768;
        char* qdst  = Qb + row * 1536;
        int   rx    = (row & 15) << 4;
        #pragma unroll
        for (int j = 0; j < 24; ++j) {
            int c4 = c0 + j * 8;
            f32x4v q4 = *(const f32x4v*)(qrow + c4 * 4);
            bf16x4 hq = { (__bf16)(q4[0] * scale2), (__bf16)(q4[1] * scale2),
                          (__bf16)(q4[2] * scale2), (__bf16)(q4[3] * scale2) };
            *(bf16x4*)(qdst + ((c4 * 8) ^ rx)) = hq;
        }
    }
    __syncthreads();
    f32x16 acc[6];
    #pragma unroll
    for (int ch = 0; ch < 6; ++ch)
        #pragma unroll
        for (int r = 0; r < 16; ++r) acc[ch][r] = 0.0f;
    float m_st = -3e38f, l_st = 0.0f;
    const int  qrow_g = mr * 32 + l31;
    const int  qglob  = qt * 64 + qrow_g;
    char*      qfbase = Qb + qrow_g * 1536;
    const int  qx     = (qrow_g & 15) << 4;
    char*      pfbase = Pb + qrow_g * 256;
    const int  vrow   = nc * 32 + l31;
    char*      vfbase = Vb + vrow * 256;
    const int  vx     = (vrow & 15) << 4;
    const int  diag_tile = qt >> 1;
    const int  srg = tid & 31, scg = tid >> 5;
    #pragma unroll 1
    for (int t = 0; t < 8; ++t) {
        const size_t kvbase = ((size_t)batch * 1024 + (size_t)t * 128) * 768;
        f32x16 s;
        #pragma unroll
        for (int r = 0; r < 16; ++r) s[r] = 0.0f;
        const float* kptr = Kg + kvbase + (size_t)(nc * 32 + l31) * 768 + 8 * half;
        #pragma unroll
        for (int ch = 0; ch < 6; ++ch) {
            #pragma unroll
            for (int ks = 0; ks < 8; ++ks) {
                f32x4v k0 = *(const f32x4v*)(kptr + ch * 128 + ks * 16);
                f32x4v k1 = *(const f32x4v*)(kptr + ch * 128 + ks * 16 + 4);
                bf16x8 kf = { (__bf16)k0[0], (__bf16)k0[1], (__bf16)k0[2], (__bf16)k0[3],
                              (__bf16)k1[0], (__bf16)k1[1], (__bf16)k1[2], (__bf16)k1[3] };
                bf16x8 qf = *(const bf16x8*)(qfbase + ((ch * 256 + ks * 32 + half * 16) ^ qx));
                s = __builtin_amdgcn_mfma_f32_32x32x16_bf16(kf, qf, s, 0, 0, 0);
            }
        }
        if (t == diag_tile) {
            #pragma unroll
            for (int r = 0; r < 16; ++r) {
                int kvg = t * 128 + nc * 32 + (r & 3) + 8 * (r >> 2) + 4 * half;
                if (kvg == qglob) s[r] = -3e38f;
            }
        }
        f32x4v vr[2][4];
        fb_stage_load(vr, Vg, kvbase, srg, scg, 0);
        float pm = s[0];
        #pragma unroll
        for (int r = 1; r < 16; ++r) pm = fmaxf(pm, s[r]);
        pm = fmaxf(pm, __shfl_xor(pm, 32, 64));
        if (half == 0) red_m[qrow_g * 4 + nc] = pm;
        __syncthreads();
        f32x4v m4 = *(const f32x4v*)(red_m + qrow_g * 4);
        float mnew = fmaxf(fmaxf(m4[0], m4[1]), fmaxf(m4[2], m4[3]));
        mnew = fmaxf(mnew, m_st);
        float cf = __builtin_amdgcn_exp2f(m_st - mnew);
        m_st = mnew;
        float pl = 0.0f;
        #pragma unroll
        for (int r = 0; r < 16; ++r) {
            float e = __builtin_amdgcn_exp2f(s[r] - mnew);
            s[r] = e; pl += e;
        }
        pl += __shfl_xor(pl, 32, 64);
        l_st = l_st * cf + pl;
        #pragma unroll
        for (int ch = 0; ch < 6; ++ch)
            #pragma unroll
            for (int r = 0; r < 16; ++r) acc[ch][r] *= cf;
        #pragma unroll
        for (int g = 0; g < 4; ++g) {
            bf16x4 hp = { (__bf16)s[4*g+0], (__bf16)s[4*g+1],
                          (__bf16)s[4*g+2], (__bf16)s[4*g+3] };
            *(bf16x4*)(pfbase + ((nc * 64 + g * 16 + half * 8) ^ qx)) = hp;
        }
        fb_stage_write(vr, Vb, srg, scg);
        __syncthreads();
        bf16x8 pa[8];
        #pragma unroll
        for (int ks = 0; ks < 8; ++ks)
            pa[ks] = *(const bf16x8*)(pfbase + ((ks * 32 + half * 16) ^ qx));
        #pragma unroll
        for (int ch = 0; ch < 6; ++ch) {
            if (ch < 5) fb_stage_load(vr, Vg, kvbase, srg, scg, ch + 1);
            #pragma unroll
            for (int ks = 0; ks < 8; ++ks) {
                bf16x8 vf = *(const bf16x8*)(vfbase + ((ks * 32 + half * 16) ^ vx));
                acc[ch] = __builtin_amdgcn_mfma_f32_32x32x16_bf16(vf, pa[ks], acc[ch], 0, 0, 0);
            }
            if (ch < 5) {
                __syncthreads();
                fb_stage_write(vr, Vb, srg, scg);
                __syncthreads();
            }
        }
    }
    if (half == 0) red_l[qrow_g * 4 + nc] = l_st;
    __syncthreads();
    f32x4v l4 = *(const f32x4v*)(red_l + qrow_g * 4);
    float rinv = 1.0f / (l4[0] + l4[1] + l4[2] + l4[3]);
    float* op = Og + ((size_t)batch * 1024 + (size_t)qglob) * 768;
    #pragma unroll
    for (int ch = 0; ch < 6; ++ch)
        #pragma unroll
        for (int g = 0; g < 4; ++g) {
            f32x4v o4 = { acc[ch][4*g+0] * rinv, acc[ch][4*g+1] * rinv,
                          acc[ch][4*g+2] * rinv, acc[ch][4*g+3] * rinv };
            *(f32x4v*)(op + ch * 128 + nc * 32 + g * 8 + half * 4) = o4;
        }
}

extern "C" void kernel_launch(void* const* d_in, const int* in_sizes, int n_in,
                              void* d_out, int out_size, void* d_ws, size_t ws_size,
                              hipStream_t stream) {
    (void)in_sizes; (void)n_in; (void)out_size;
    const float* Q = (const float*)d_in[0];
    const float* K = (const float*)d_in[1];
    const float* V = (const float*)d_in[2];
    const float* T = (const float*)d_in[3];
    float* O = (float*)d_out;
    if (ws_size >= WS_NEEDED) {
        unsigned short* Qws = (unsigned short*)((char*)d_ws + WS_Q);
        unsigned short* Kws = (unsigned short*)((char*)d_ws + WS_K);
        unsigned short* Vws = (unsigned short*)((char*)d_ws + WS_V);
        prep_all<<<dim3(2048), dim3(512), 0, stream>>>(Q, K, V, T, Qws, Kws, Vws);
        lsa_main<<<dim3(1024), dim3(512), LDS_MAIN, stream>>>(Qws, Kws, Vws, O);
    } else {
        lsa_fb<<<dim3(1024), dim3(512), FB_LDS, stream>>>(Q, K, V, T, O);
    }
}

// Round 9
// 484.697 us; speedup vs baseline: 1.0193x; 1.0071x over previous
//
#include <hip/hip_runtime.h>

// LSA fused attention: out = softmax(QK^T/temp, diag=-inf) @ V
// B=64, N=1024, D=768, fp32 I/O, bf16 MFMA 32x32x16.
//
// Merged prepass rewrites Q(scaled),K,V as MFMA-fragment-ordered bf16 images
// in d_ws. Main kernel (R9): PERSISTENT 256-block grid (1 block/CU), each
// block runs 4 (batch,qt) items with XCD-aligned scheduling: each XCD's 32
// CUs process exactly 2 batches at a time, phase-aligned, so the 3 MB K/V
// working set fits the 4 MB per-XCD L2 (16x reuse -> L2 hits, not L3).
// Inner structure = R7: BKV=512/tile, K ring-5 + Q-frag LDS dbuf, V ring-2,
// P exchange via LDS sub-phases, lgkm-only barriers keep prefetches alive.

typedef __bf16 bf16x8 __attribute__((ext_vector_type(8)));
typedef __bf16 bf16x4 __attribute__((ext_vector_type(4)));
typedef float  f32x16 __attribute__((ext_vector_type(16)));
typedef float  f32x4v __attribute__((ext_vector_type(4)));

#define WS_Q 0UL
#define WS_K 100663296UL
#define WS_V 201326592UL
#define WS_NEEDED 301989888UL

#define QOFF   0          // 96 KB Q frag image (resident; reused as O-transpose)
#define POFF   98304      // 32 KB P frag blocks (one PV sub-phase)
#define REDOFF 131072     // redm 2KB + redl 2KB
#define LDS_MAIN 135168

__device__ __forceinline__ void gld16(const void* g, const char* l) {
    __builtin_amdgcn_global_load_lds(
        (const __attribute__((address_space(1))) unsigned int*)g,
        (__attribute__((address_space(3))) unsigned int*)(l), 16, 0, 0);
}

#define LGKM0_BAR() do {                                            \
    asm volatile("s_waitcnt lgkmcnt(0)" ::: "memory");              \
    __builtin_amdgcn_s_barrier();                                   \
    asm volatile("" ::: "memory"); } while (0)

// ============================ merged prepass ============================
// grid 2048 x 512 thr: bid<1024 -> Q tile (b*16+qt); <1536 -> K (b*8+t); else V.
__global__ __launch_bounds__(512) void prep_all(
    const float* __restrict__ Qg, const float* __restrict__ Kg,
    const float* __restrict__ Vg, const float* __restrict__ Tg,
    unsigned short* __restrict__ Qws, unsigned short* __restrict__ Kws,
    unsigned short* __restrict__ Vws)
{
    __shared__ __align__(16) char Lraw[34816];
    const int bid = blockIdx.x;
    const int tid = threadIdx.x;

    if (bid < 1024) {
        // ---- Q: 64x768, scaled, -> frag image ----
        const float scale2 = 1.4426950408889634f / Tg[0];   // log2(e)/temp
        const float* src = Qg + (size_t)bid * 49152;
        char* outb = (char*)Qws + (size_t)bid * 98304;
        const int row = tid >> 3;
        const int c0  = tid & 7;            // 8 cols of 8 floats
        #pragma unroll 1
        for (int st = 0; st < 12; ++st) {
            #pragma unroll
            for (int i = 0; i < 2; ++i) {
                f32x4v v = *(const f32x4v*)(src + (size_t)row * 768 + st * 64 + c0 * 8 + i * 4);
                bf16x4 hb = { (__bf16)(v[0] * scale2), (__bf16)(v[1] * scale2),
                              (__bf16)(v[2] * scale2), (__bf16)(v[3] * scale2) };
                *(bf16x4*)(Lraw + row * 144 + (c0 * 8 + i * 4) * 2) = hb;
            }
            __syncthreads();
            {
                int u = tid;                               // [0,512)
                int ks = u >> 7, mrr = (u >> 6) & 1, l = u & 63;
                bf16x8 f = *(const bf16x8*)(Lraw + (mrr * 32 + (l & 31)) * 144
                                            + ks * 32 + 16 * (l >> 5));
                *(bf16x8*)(outb + (size_t)st * 8192 + u * 16) = f;
            }
            __syncthreads();
        }
    } else if (bid < 1536) {
        // ---- K: 128x768 -> frag image ----
        const int b2 = bid - 1024;
        const float* src = Kg + (size_t)b2 * 98304;
        char* outb = (char*)Kws + (size_t)b2 * 196608;
        const int kv = tid >> 2;
        const int k0 = (tid & 3) * 16;
        #pragma unroll 1
        for (int st = 0; st < 12; ++st) {
            #pragma unroll
            for (int i = 0; i < 4; ++i) {
                f32x4v v = *(const f32x4v*)(src + (size_t)kv * 768 + st * 64 + k0 + i * 4);
                bf16x4 hb = { (__bf16)v[0], (__bf16)v[1], (__bf16)v[2], (__bf16)v[3] };
                *(bf16x4*)(Lraw + kv * 144 + (k0 + i * 4) * 2) = hb;
            }
            __syncthreads();
            #pragma unroll
            for (int i = 0; i < 2; ++i) {
                int u = tid * 2 + i;                       // [0,1024)
                int ks = u >> 8, ncc = (u >> 6) & 3, l = u & 63;
                bf16x8 f = *(const bf16x8*)(Lraw + (ncc * 32 + (l & 31)) * 144
                                            + ks * 32 + 16 * (l >> 5));
                *(bf16x8*)(outb + (size_t)st * 16384 + u * 16) = f;
            }
            __syncthreads();
        }
    } else {
        // ---- V: 128x768 -> transposed frag image ----
        const int b2 = bid - 1536;
        const float* src = Vg + (size_t)b2 * 98304;
        char* outb = (char*)Vws + (size_t)b2 * 196608;
        const int srg = tid & 31, scg = tid >> 5;
        #pragma unroll 1
        for (int jg = 0; jg < 6; ++jg) {
            #pragma unroll
            for (int i2 = 0; i2 < 2; ++i2) {
                int cg = scg + i2 * 16;
                const float* vp = src + (size_t)(srg * 4) * 768 + jg * 128 + cg * 4;
                f32x4v a0 = *(const f32x4v*)(vp);
                f32x4v a1 = *(const f32x4v*)(vp + 768);
                f32x4v a2 = *(const f32x4v*)(vp + 1536);
                f32x4v a3 = *(const f32x4v*)(vp + 2304);
                #pragma unroll
                for (int c = 0; c < 4; ++c) {
                    int d = cg * 4 + c;
                    bf16x4 hb = { (__bf16)a0[c], (__bf16)a1[c], (__bf16)a2[c], (__bf16)a3[c] };
                    *(bf16x4*)(Lraw + d * 272 + srg * 8) = hb;
                }
            }
            __syncthreads();
            #pragma unroll
            for (int i = 0; i < 4; ++i) {
                int u = tid * 4 + i;                       // [0,2048)
                int kh = u >> 10, ks = (u >> 8) & 3, ncc = (u >> 6) & 3, l = u & 63;
                bf16x8 f = *(const bf16x8*)(Lraw + (ncc * 32 + (l & 31)) * 272
                                            + kh * 128 + ks * 32 + 16 * (l >> 5));
                *(bf16x8*)(outb + (size_t)(jg * 2 + kh) * 16384 + (u & 1023) * 16) = f;
            }
            __syncthreads();
        }
    }
}

// ============================ main kernel (persistent) ============================
#define OFFK(st)  ((size_t)((st) >> 2) * 16384 + (size_t)((st) & 3) * 4096)
#define OFFV(ks)  ((size_t)((ks) >> 3) * 196608 + (size_t)(((ks) >> 2) & 1) * 16384 \
                   + (size_t)((ks) & 3) * 4096)

__global__ __launch_bounds__(512, 2) void lsa_main(
    const unsigned short* __restrict__ Qws, const unsigned short* __restrict__ Kws,
    const unsigned short* __restrict__ Vws, float* __restrict__ Og)
{
    extern __shared__ char sm[];
    const int tid  = threadIdx.x;
    const int lane = tid & 63;
    const int w    = tid >> 6;
    const int hh   = lane >> 5;
    const int l31  = lane & 31;

    const int id  = blockIdx.x;          // [0,256), 1 block per CU
    const int xcd = id & 7;
    const int c   = id >> 3;             // CU-local index within XCD [0,32)
    const int qt  = c & 15;

    float* redm = (float*)(sm + REDOFF);
    float* redl = (float*)(sm + REDOFF + 2048);

    // per-wave invariant offsets
    const size_t kwoffs = (size_t)(w >> 1) * 196608 + (size_t)(w & 1) * 2048
                          + (size_t)lane * 16;
    size_t voff3[3];
    #pragma unroll
    for (int g3 = 0; g3 < 3; ++g3) {
        int dgi = w * 3 + g3;
        voff3[g3] = (size_t)(dgi >> 2) * 32768 + (size_t)(dgi & 3) * 1024
                    + (size_t)lane * 16;
    }
    const int diag_t2 = qt >> 3;
    const int wlo = (w < 4);

    #pragma unroll 1
    for (int item = 0; item < 4; ++item) {
        // XCD-aligned work: during item i, XCD x serves batches {x*8+2i, x*8+2i+1}
        const int batch = xcd * 8 + item * 2 + (c >> 4);

        const char* qimg = (const char*)Qws + (size_t)(batch * 16 + qt) * 98304;
        const char* kimg = (const char*)Kws + (size_t)batch * 1572864;
        const char* vimg = (const char*)Vws + (size_t)batch * 1572864;

        // ---- stage Q image (96 KB) into LDS ----
        #pragma unroll
        for (int i = 0; i < 12; ++i)
            gld16(qimg + i * 8192 + tid * 16, sm + QOFF + i * 8192 + w * 1024);
        __syncthreads();

        f32x16 acc[3][2];
        #pragma unroll
        for (int g3 = 0; g3 < 3; ++g3)
            #pragma unroll
            for (int qg = 0; qg < 2; ++qg)
                #pragma unroll
                for (int r = 0; r < 16; ++r) acc[g3][qg][r] = 0.0f;
        float m_st[2] = { -3e38f, -3e38f };
        float l_st[2] = { 0.0f, 0.0f };

        const char* kbase = kimg + kwoffs;

        #pragma unroll 1
        for (int t2 = 0; t2 < 2; ++t2) {
            // ========== QK^T: 48 steps x 4 MFMA, dbuf qf + ring-5 K ==========
            const char* kb = kbase + (size_t)t2 * 786432;
            f32x16 s[2][2];
            #pragma unroll
            for (int kk = 0; kk < 2; ++kk)
                #pragma unroll
                for (int qg = 0; qg < 2; ++qg)
                    #pragma unroll
                    for (int r = 0; r < 16; ++r) s[kk][qg][r] = 0.0f;

            bf16x8 kr0[5], kr1[5];
            #pragma unroll
            for (int p = 0; p < 5; ++p) {
                kr0[p] = *(const bf16x8*)(kb + OFFK(p));
                kr1[p] = *(const bf16x8*)(kb + OFFK(p) + 1024);
            }
            bf16x8 qf[2][2];
            qf[0][0] = *(const bf16x8*)(sm + QOFF + 0 + lane * 16);
            qf[0][1] = *(const bf16x8*)(sm + QOFF + 1024 + lane * 16);

            #pragma unroll
            for (int st = 0; st < 48; ++st) {
                const int cur = st & 1, nxt = cur ^ 1;
                if (st < 47) {
                    qf[nxt][0] = *(const bf16x8*)(sm + QOFF + ((st + 1) * 2 + 0) * 1024 + lane * 16);
                    qf[nxt][1] = *(const bf16x8*)(sm + QOFF + ((st + 1) * 2 + 1) * 1024 + lane * 16);
                }
                __builtin_amdgcn_s_setprio(1);
                s[0][0] = __builtin_amdgcn_mfma_f32_32x32x16_bf16(kr0[st % 5], qf[cur][0], s[0][0], 0, 0, 0);
                s[0][1] = __builtin_amdgcn_mfma_f32_32x32x16_bf16(kr0[st % 5], qf[cur][1], s[0][1], 0, 0, 0);
                s[1][0] = __builtin_amdgcn_mfma_f32_32x32x16_bf16(kr1[st % 5], qf[cur][0], s[1][0], 0, 0, 0);
                s[1][1] = __builtin_amdgcn_mfma_f32_32x32x16_bf16(kr1[st % 5], qf[cur][1], s[1][1], 0, 0, 0);
                __builtin_amdgcn_s_setprio(0);
                if (st < 43) {
                    kr0[st % 5] = *(const bf16x8*)(kb + OFFK(st + 5));
                    kr1[st % 5] = *(const bf16x8*)(kb + OFFK(st + 5) + 1024);
                }
            }

            // ---- V ring warm-up (lands under softmax) ----
            const char* vbt = vimg + (size_t)t2 * 786432;
            bf16x8 vrg[2][3];
            #pragma unroll
            for (int p = 0; p < 2; ++p)
                #pragma unroll
                for (int g3 = 0; g3 < 3; ++g3)
                    vrg[p][g3] = *(const bf16x8*)(vbt + voff3[g3] + OFFV(p));

            // diagonal self-exclusion
            if (t2 == diag_t2) {
                #pragma unroll
                for (int kk = 0; kk < 2; ++kk)
                    #pragma unroll
                    for (int qg = 0; qg < 2; ++qg)
                        #pragma unroll
                        for (int r = 0; r < 16; ++r) {
                            int kvg = t2 * 512 + w * 64 + kk * 32 + (r & 3) + 8 * (r >> 2) + 4 * hh;
                            if (kvg == qt * 64 + qg * 32 + l31) s[kk][qg][r] = -3e38f;
                        }
            }

            // ================= online softmax =================
            #pragma unroll
            for (int qg = 0; qg < 2; ++qg) {
                float pm = s[0][qg][0];
                #pragma unroll
                for (int r = 1; r < 16; ++r) pm = fmaxf(pm, s[0][qg][r]);
                #pragma unroll
                for (int r = 0; r < 16; ++r) pm = fmaxf(pm, s[1][qg][r]);
                pm = fmaxf(pm, __shfl_xor(pm, 32, 64));
                if (hh == 0) redm[(qg * 32 + l31) * 8 + w] = pm;
            }
            LGKM0_BAR();                           // bar1
            float cf[2];
            #pragma unroll
            for (int qg = 0; qg < 2; ++qg) {
                const float* rp = redm + (qg * 32 + l31) * 8;
                f32x4v a = *(const f32x4v*)rp;
                f32x4v b = *(const f32x4v*)(rp + 4);
                float mn = fmaxf(fmaxf(fmaxf(a[0], a[1]), fmaxf(a[2], a[3])),
                                 fmaxf(fmaxf(b[0], b[1]), fmaxf(b[2], b[3])));
                mn = fmaxf(mn, m_st[qg]);
                cf[qg] = __builtin_amdgcn_exp2f(m_st[qg] - mn);
                m_st[qg] = mn;
                float pl = 0.0f;
                #pragma unroll
                for (int kk = 0; kk < 2; ++kk)
                    #pragma unroll
                    for (int r = 0; r < 16; ++r) {
                        float e = __builtin_amdgcn_exp2f(s[kk][qg][r] - mn);
                        s[kk][qg][r] = e; pl += e;
                    }
                pl += __shfl_xor(pl, 32, 64);
                l_st[qg] = l_st[qg] * cf[qg] + pl;
            }

            #define WRITE_P() do {                                                      \
                _Pragma("unroll")                                                       \
                for (int kk = 0; kk < 2; ++kk)                                          \
                    _Pragma("unroll")                                                   \
                    for (int g = 0; g < 4; ++g)                                         \
                        _Pragma("unroll")                                               \
                        for (int qg = 0; qg < 2; ++qg) {                                \
                            bf16x4 p4 = { (__bf16)s[kk][qg][4*g+0], (__bf16)s[kk][qg][4*g+1], \
                                          (__bf16)s[kk][qg][4*g+2], (__bf16)s[kk][qg][4*g+3] }; \
                            int bidx = (((w & 3) * 4 + kk * 2 + (g >> 1)) * 2 + qg);    \
                            *(bf16x4*)(sm + POFF + bidx * 1024                          \
                                       + ((g & 1) * 32 + l31) * 16 + hh * 8) = p4;      \
                        } } while (0)

            if (wlo) WRITE_P();                    // waves 0-3: kv 0..255

            // acc rescale AFTER P writes (overlaps ds_write/barrier)
            #pragma unroll
            for (int g3 = 0; g3 < 3; ++g3)
                #pragma unroll
                for (int qg = 0; qg < 2; ++qg)
                    #pragma unroll
                    for (int r = 0; r < 16; ++r) acc[g3][qg][r] *= cf[qg];

            LGKM0_BAR();                           // bar2: P-A ready

            // ============ PV sub-phase A: lk 0..15, dbuf pa + ring-2 V ============
            bf16x8 pa[2][2];
            pa[0][0] = *(const bf16x8*)(sm + POFF + 0 + lane * 16);
            pa[0][1] = *(const bf16x8*)(sm + POFF + 1024 + lane * 16);
            #pragma unroll
            for (int lk = 0; lk < 16; ++lk) {
                const int cur = lk & 1, nxt = cur ^ 1;
                if (lk < 15) {
                    pa[nxt][0] = *(const bf16x8*)(sm + POFF + ((lk + 1) * 2 + 0) * 1024 + lane * 16);
                    pa[nxt][1] = *(const bf16x8*)(sm + POFF + ((lk + 1) * 2 + 1) * 1024 + lane * 16);
                }
                __builtin_amdgcn_s_setprio(1);
                #pragma unroll
                for (int g3 = 0; g3 < 3; ++g3) {
                    acc[g3][0] = __builtin_amdgcn_mfma_f32_32x32x16_bf16(vrg[lk & 1][g3], pa[cur][0], acc[g3][0], 0, 0, 0);
                    acc[g3][1] = __builtin_amdgcn_mfma_f32_32x32x16_bf16(vrg[lk & 1][g3], pa[cur][1], acc[g3][1], 0, 0, 0);
                }
                __builtin_amdgcn_s_setprio(0);
                #pragma unroll
                for (int g3 = 0; g3 < 3; ++g3)
                    vrg[lk & 1][g3] = *(const bf16x8*)(vbt + voff3[g3] + OFFV(lk + 2));
            }
            LGKM0_BAR();                           // bar3: P-A reads done
            if (!wlo) WRITE_P();                   // waves 4-7: kv 256..511
            LGKM0_BAR();                           // bar4: P-B ready

            // ================= PV sub-phase B: lk 16..31 =================
            pa[0][0] = *(const bf16x8*)(sm + POFF + 0 + lane * 16);
            pa[0][1] = *(const bf16x8*)(sm + POFF + 1024 + lane * 16);
            #pragma unroll
            for (int lk = 16; lk < 32; ++lk) {
                const int cur = lk & 1, nxt = cur ^ 1;
                if (lk < 31) {
                    pa[nxt][0] = *(const bf16x8*)(sm + POFF + ((lk - 15) * 2 + 0) * 1024 + lane * 16);
                    pa[nxt][1] = *(const bf16x8*)(sm + POFF + ((lk - 15) * 2 + 1) * 1024 + lane * 16);
                }
                __builtin_amdgcn_s_setprio(1);
                #pragma unroll
                for (int g3 = 0; g3 < 3; ++g3) {
                    acc[g3][0] = __builtin_amdgcn_mfma_f32_32x32x16_bf16(vrg[lk & 1][g3], pa[cur][0], acc[g3][0], 0, 0, 0);
                    acc[g3][1] = __builtin_amdgcn_mfma_f32_32x32x16_bf16(vrg[lk & 1][g3], pa[cur][1], acc[g3][1], 0, 0, 0);
                }
                __builtin_amdgcn_s_setprio(0);
                if (lk < 30) {
                    #pragma unroll
                    for (int g3 = 0; g3 < 3; ++g3)
                        vrg[lk & 1][g3] = *(const bf16x8*)(vbt + voff3[g3] + OFFV(lk + 2));
                }
            }
            #undef WRITE_P
        }

        // ================= epilogue =================
        #pragma unroll
        for (int qg = 0; qg < 2; ++qg)
            if (hh == 0) redl[(qg * 32 + l31) * 8 + w] = l_st[qg];
        __syncthreads();
        float rinv[2];
        #pragma unroll
        for (int qg = 0; qg < 2; ++qg) {
            const float* rp = redl + (qg * 32 + l31) * 8;
            f32x4v a = *(const f32x4v*)rp;
            f32x4v b = *(const f32x4v*)(rp + 4);
            rinv[qg] = 1.0f / (a[0] + a[1] + a[2] + a[3] + b[0] + b[1] + b[2] + b[3]);
        }

        char* obt = sm + QOFF;                 // reuse Q space: [64 q][256 d] f32
        const size_t orow = (size_t)batch * 1024 + (size_t)qt * 64;
        const int q2 = tid >> 3, c8 = tid & 7;

        #pragma unroll
        for (int g3 = 0; g3 < 3; ++g3) {
            __syncthreads();
            #pragma unroll
            for (int qg = 0; qg < 2; ++qg) {
                int q = qg * 32 + l31;
                int qx = (q & 15) << 4;
                #pragma unroll
                for (int g = 0; g < 4; ++g) {
                    f32x4v o4 = { acc[g3][qg][4 * g + 0] * rinv[qg],
                                  acc[g3][qg][4 * g + 1] * rinv[qg],
                                  acc[g3][qg][4 * g + 2] * rinv[qg],
                                  acc[g3][qg][4 * g + 3] * rinv[qg] };
                    int dloc = w * 32 + 8 * g + 4 * hh;
                    *(f32x4v*)(obt + q * 1024 + ((dloc * 4) ^ qx)) = o4;
                }
            }
            __syncthreads();
            #pragma unroll
            for (int i = 0; i < 8; ++i) {
                int db = c8 * 128 + i * 16;
                f32x4v o = *(const f32x4v*)(obt + q2 * 1024 + (db ^ ((q2 & 15) << 4)));
                int dg = c8 * 96 + g3 * 32 + i * 4;
                *(f32x4v*)(Og + (orow + q2) * 768 + dg) = o;
            }
        }
        __syncthreads();                       // obt reads done before next item's Q stage
    }
}

// ============================ fallback (round-2 kernel) ============================
__device__ __forceinline__ void fb_stage_load(f32x4v (&vr)[2][4], const float* __restrict__ Vg,
                                              size_t kvbase, int srg, int scg, int ch) {
    #pragma unroll
    for (int i2 = 0; i2 < 2; ++i2) {
        const float* vp = Vg + kvbase + (size_t)(srg * 4) * 768 + ch * 128 + (scg + i2 * 16) * 4;
        #pragma unroll
        for (int rr = 0; rr < 4; ++rr)
            vr[i2][rr] = *(const f32x4v*)(vp + (size_t)rr * 768);
    }
}
__device__ __forceinline__ void fb_stage_write(const f32x4v (&vr)[2][4], char* Vb, int srg, int scg) {
    #pragma unroll
    for (int i2 = 0; i2 < 2; ++i2) {
        int cg = scg + i2 * 16;
        #pragma unroll
        for (int q4 = 0; q4 < 4; ++q4) {
            int drow = cg * 4 + q4;
            bf16x4 hv = { (__bf16)vr[i2][0][q4], (__bf16)vr[i2][1][q4],
                          (__bf16)vr[i2][2][q4], (__bf16)vr[i2][3][q4] };
            *(bf16x4*)(Vb + drow * 256 + ((srg * 8) ^ ((drow & 15) << 4))) = hv;
        }
    }
}
#define FB_OFF_V  98304
#define FB_OFF_P  131072
#define FB_OFF_RM 147456
#define FB_OFF_RL 148480
#define FB_LDS    149504
__global__ __launch_bounds__(512) void lsa_fb(
    const float* __restrict__ Qg, const float* __restrict__ Kg,
    const float* __restrict__ Vg, const float* __restrict__ Tg,
    float* __restrict__ Og)
{
    extern __shared__ char smem[];
    char*  Qb    = smem;
    char*  Vb    = smem + FB_OFF_V;
    char*  Pb    = smem + FB_OFF_P;
    float* red_m = (float*)(smem + FB_OFF_RM);
    float* red_l = (float*)(smem + FB_OFF_RL);
    const int tid  = threadIdx.x;
    const int lane = tid & 63;
    const int w    = tid >> 6;
    const int mr   = w & 1;
    const int nc   = w >> 1;
    const int half = lane >> 5;
    const int l31  = lane & 31;
    int id = blockIdx.x, xcd = id & 7, jj = id >> 3;
    int batch = (jj >> 5) * 16 + xcd * 2 + ((jj >> 4) & 1);
    int qt = jj & 15;
    const float scale2 = 1.4426950408889634f / Tg[0];
    {
        const float* qp   = Qg + ((size_t)batch * 1024 + (size_t)qt * 64) * 768;
        int   row   = tid >> 3, c0 = tid & 7;
        const float* qrow = qp + (size_t)row * 768;
        char* qdst  = Qb + row * 1536;
        int   rx    = (row & 15) << 4;
        #pragma unroll
        for (int j = 0; j < 24; ++j) {
            int c4 = c0 + j * 8;
            f32x4v q4 = *(const f32x4v*)(qrow + c4 * 4);
            bf16x4 hq = { (__bf16)(q4[0] * scale2), (__bf16)(q4[1] * scale2),
                          (__bf16)(q4[2] * scale2), (__bf16)(q4[3] * scale2) };
            *(bf16x4*)(qdst + ((c4 * 8) ^ rx)) = hq;
        }
    }
    __syncthreads();
    f32x16 acc[6];
    #pragma unroll
    for (int ch = 0; ch < 6; ++ch)
        #pragma unroll
        for (int r = 0; r < 16; ++r) acc[ch][r] = 0.0f;
    float m_st = -3e38f, l_st = 0.0f;
    const int  qrow_g = mr * 32 + l31;
    const int  qglob  = qt * 64 + qrow_g;
    char*      qfbase = Qb + qrow_g * 1536;
    const int  qx     = (qrow_g & 15) << 4;
    char*      pfbase = Pb + qrow_g * 256;
    const int  vrow   = nc * 32 + l31;
    char*      vfbase = Vb + vrow * 256;
    const int  vx     = (vrow & 15) << 4;
    const int  diag_tile = qt >> 1;
    const int  srg = tid & 31, scg = tid >> 5;
    #pragma unroll 1
    for (int t = 0; t < 8; ++t) {
        const size_t kvbase = ((size_t)batch * 1024 + (size_t)t * 128) * 768;
        f32x16 s;
        #pragma unroll
        for (int r = 0; r < 16; ++r) s[r] = 0.0f;
        const float* kptr = Kg + kvbase + (size_t)(nc * 32 + l31) * 768 + 8 * half;
        #pragma unroll
        for (int ch = 0; ch < 6; ++ch) {
            #pragma unroll
            for (int ks = 0; ks < 8; ++ks) {
                f32x4v k0 = *(const f32x4v*)(kptr + ch * 128 + ks * 16);
                f32x4v k1 = *(const f32x4v*)(kptr + ch * 128 + ks * 16 + 4);
                bf16x8 kf = { (__bf16)k0[0], (__bf16)k0[1], (__bf16)k0[2], (__bf16)k0[3],
                              (__bf16)k1[0], (__bf16)k1[1], (__bf16)k1[2], (__bf16)k1[3] };
                bf16x8 qf = *(const bf16x8*)(qfbase + ((ch * 256 + ks * 32 + half * 16) ^ qx));
                s = __builtin_amdgcn_mfma_f32_32x32x16_bf16(kf, qf, s, 0, 0, 0);
            }
        }
        if (t == diag_tile) {
            #pragma unroll
            for (int r = 0; r < 16; ++r) {
                int kvg = t * 128 + nc * 32 + (r & 3) + 8 * (r >> 2) + 4 * half;
                if (kvg == qglob) s[r] = -3e38f;
            }
        }
        f32x4v vr[2][4];
        fb_stage_load(vr, Vg, kvbase, srg, scg, 0);
        float pm = s[0];
        #pragma unroll
        for (int r = 1; r < 16; ++r) pm = fmaxf(pm, s[r]);
        pm = fmaxf(pm, __shfl_xor(pm, 32, 64));
        if (half == 0) red_m[qrow_g * 4 + nc] = pm;
        __syncthreads();
        f32x4v m4 = *(const f32x4v*)(red_m + qrow_g * 4);
        float mnew = fmaxf(fmaxf(m4[0], m4[1]), fmaxf(m4[2], m4[3]));
        mnew = fmaxf(mnew, m_st);
        float cf = __builtin_amdgcn_exp2f(m_st - mnew);
        m_st = mnew;
        float pl = 0.0f;
        #pragma unroll
        for (int r = 0; r < 16; ++r) {
            float e = __builtin_amdgcn_exp2f(s[r] - mnew);
            s[r] = e; pl += e;
        }
        pl += __shfl_xor(pl, 32, 64);
        l_st = l_st * cf + pl;
        #pragma unroll
        for (int ch = 0; ch < 6; ++ch)
            #pragma unroll
            for (int r = 0; r < 16; ++r) acc[ch][r] *= cf;
        #pragma unroll
        for (int g = 0; g < 4; ++g) {
            bf16x4 hp = { (__bf16)s[4*g+0], (__bf16)s[4*g+1],
                          (__bf16)s[4*g+2], (__bf16)s[4*g+3] };
            *(bf16x4*)(pfbase + ((nc * 64 + g * 16 + half * 8) ^ qx)) = hp;
        }
        fb_stage_write(vr, Vb, srg, scg);
        __syncthreads();
        bf16x8 pa[8];
        #pragma unroll
        for (int ks = 0; ks < 8; ++ks)
            pa[ks] = *(const bf16x8*)(pfbase + ((ks * 32 + half * 16) ^ qx));
        #pragma unroll
        for (int ch = 0; ch < 6; ++ch) {
            if (ch < 5) fb_stage_load(vr, Vg, kvbase, srg, scg, ch + 1);
            #pragma unroll
            for (int ks = 0; ks < 8; ++ks) {
                bf16x8 vf = *(const bf16x8*)(vfbase + ((ks * 32 + half * 16) ^ vx));
                acc[ch] = __builtin_amdgcn_mfma_f32_32x32x16_bf16(vf, pa[ks], acc[ch], 0, 0, 0);
            }
            if (ch < 5) {
                __syncthreads();
                fb_stage_write(vr, Vb, srg, scg);
                __syncthreads();
            }
        }
    }
    if (half == 0) red_l[qrow_g * 4 + nc] = l_st;
    __syncthreads();
    f32x4v l4 = *(const f32x4v*)(red_l + qrow_g * 4);
    float rinv = 1.0f / (l4[0] + l4[1] + l4[2] + l4[3]);
    float* op = Og + ((size_t)batch * 1024 + (size_t)qglob) * 768;
    #pragma unroll
    for (int ch = 0; ch < 6; ++ch)
        #pragma unroll
        for (int g = 0; g < 4; ++g) {
            f32x4v o4 = { acc[ch][4*g+0] * rinv, acc[ch][4*g+1] * rinv,
                          acc[ch][4*g+2] * rinv, acc[ch][4*g+3] * rinv };
            *(f32x4v*)(op + ch * 128 + nc * 32 + g * 8 + half * 4) = o4;
        }
}

extern "C" void kernel_launch(void* const* d_in, const int* in_sizes, int n_in,
                              void* d_out, int out_size, void* d_ws, size_t ws_size,
                              hipStream_t stream) {
    (void)in_sizes; (void)n_in; (void)out_size;
    const float* Q = (const float*)d_in[0];
    const float* K = (const float*)d_in[1];
    const float* V = (const float*)d_in[2];
    const float* T = (const float*)d_in[3];
    float* O = (float*)d_out;
    if (ws_size >= WS_NEEDED) {
        unsigned short* Qws = (unsigned short*)((char*)d_ws + WS_Q);
        unsigned short* Kws = (unsigned short*)((char*)d_ws + WS_K);
        unsigned short* Vws = (unsigned short*)((char*)d_ws + WS_V);
        prep_all<<<dim3(2048), dim3(512), 0, stream>>>(Q, K, V, T, Qws, Kws, Vws);
        lsa_main<<<dim3(256), dim3(512), LDS_MAIN, stream>>>(Qws, Kws, Vws, O);
    } else {
        lsa_fb<<<dim3(1024), dim3(512), FB_LDS, stream>>>(Q, K, V, T, O);
    }
}

// Round 10
// 445.470 us; speedup vs baseline: 1.1091x; 1.0881x over previous
//
#include <hip/hip_runtime.h>

// LSA fused attention: out = softmax(QK^T/temp, diag=-inf) @ V
// B=64, N=1024, D=768, fp32 I/O, bf16 MFMA 32x32x16.
//
// Prepass rewrites K,V as MFMA-fragment-ordered bf16 images in d_ws
// (Q prep FUSED into main: fp32 Q staged+converted to frag layout in LDS
// directly -- saves ~290MB of prep traffic). Main: BKV=512/tile, 64 kv per
// wave; K/V frags global->reg (each byte once per block) with rings
// (K:5, V:2); Q-frag LDS dbuf; P exchange via LDS sub-phases; lgkm-only
// barriers keep global prefetches alive across sync.
// Known wall (R5-R9): main pinned at ~3.07GB/block-aggregate inbound
// over ~10.6 TB/s beyond-L1 supply; q-tile>64 blocked by register file.

typedef __bf16 bf16x8 __attribute__((ext_vector_type(8)));
typedef __bf16 bf16x4 __attribute__((ext_vector_type(4)));
typedef float  f32x16 __attribute__((ext_vector_type(16)));
typedef float  f32x4v __attribute__((ext_vector_type(4)));

#define WS_K 0UL
#define WS_V 100663296UL
#define WS_NEEDED 201326592UL

#define QOFF   0          // 96 KB Q frag image (built in-kernel; reused as O-transpose)
#define POFF   98304      // 32 KB P frag blocks (one PV sub-phase)
#define REDOFF 131072     // redm 2KB + redl 2KB
#define LDS_MAIN 135168

#define LGKM0_BAR() do {                                            \
    asm volatile("s_waitcnt lgkmcnt(0)" ::: "memory");              \
    __builtin_amdgcn_s_barrier();                                   \
    asm volatile("" ::: "memory"); } while (0)

// ============================ prepass (K + V only) ============================
// grid 1024 x 512 thr: bid<512 -> K (b*8+t); else V (b*8+t).
__global__ __launch_bounds__(512) void prep_kv(
    const float* __restrict__ Kg, const float* __restrict__ Vg,
    unsigned short* __restrict__ Kws, unsigned short* __restrict__ Vws)
{
    __shared__ __align__(16) char Lraw[34816];
    const int bid = blockIdx.x;
    const int tid = threadIdx.x;

    if (bid < 512) {
        // ---- K: 128x768 -> frag image ----
        const float* src = Kg + (size_t)bid * 98304;
        char* outb = (char*)Kws + (size_t)bid * 196608;
        const int kv = tid >> 2;
        const int k0 = (tid & 3) * 16;
        #pragma unroll 1
        for (int st = 0; st < 12; ++st) {
            #pragma unroll
            for (int i = 0; i < 4; ++i) {
                f32x4v v = *(const f32x4v*)(src + (size_t)kv * 768 + st * 64 + k0 + i * 4);
                bf16x4 hb = { (__bf16)v[0], (__bf16)v[1], (__bf16)v[2], (__bf16)v[3] };
                *(bf16x4*)(Lraw + kv * 144 + (k0 + i * 4) * 2) = hb;
            }
            __syncthreads();
            #pragma unroll
            for (int i = 0; i < 2; ++i) {
                int u = tid * 2 + i;                       // [0,1024)
                int ks = u >> 8, ncc = (u >> 6) & 3, l = u & 63;
                bf16x8 f = *(const bf16x8*)(Lraw + (ncc * 32 + (l & 31)) * 144
                                            + ks * 32 + 16 * (l >> 5));
                *(bf16x8*)(outb + (size_t)st * 16384 + u * 16) = f;
            }
            __syncthreads();
        }
    } else {
        // ---- V: 128x768 -> transposed frag image ----
        const int b2 = bid - 512;
        const float* src = Vg + (size_t)b2 * 98304;
        char* outb = (char*)Vws + (size_t)b2 * 196608;
        const int srg = tid & 31, scg = tid >> 5;
        #pragma unroll 1
        for (int jg = 0; jg < 6; ++jg) {
            #pragma unroll
            for (int i2 = 0; i2 < 2; ++i2) {
                int cg = scg + i2 * 16;
                const float* vp = src + (size_t)(srg * 4) * 768 + jg * 128 + cg * 4;
                f32x4v a0 = *(const f32x4v*)(vp);
                f32x4v a1 = *(const f32x4v*)(vp + 768);
                f32x4v a2 = *(const f32x4v*)(vp + 1536);
                f32x4v a3 = *(const f32x4v*)(vp + 2304);
                #pragma unroll
                for (int c = 0; c < 4; ++c) {
                    int d = cg * 4 + c;
                    bf16x4 hb = { (__bf16)a0[c], (__bf16)a1[c], (__bf16)a2[c], (__bf16)a3[c] };
                    *(bf16x4*)(Lraw + d * 272 + srg * 8) = hb;
                }
            }
            __syncthreads();
            #pragma unroll
            for (int i = 0; i < 4; ++i) {
                int u = tid * 4 + i;                       // [0,2048)
                int kh = u >> 10, ks = (u >> 8) & 3, ncc = (u >> 6) & 3, l = u & 63;
                bf16x8 f = *(const bf16x8*)(Lraw + (ncc * 32 + (l & 31)) * 272
                                            + kh * 128 + ks * 32 + 16 * (l >> 5));
                *(bf16x8*)(outb + (size_t)(jg * 2 + kh) * 16384 + (u & 1023) * 16) = f;
            }
            __syncthreads();
        }
    }
}

// ============================ main kernel ============================
#define OFFK(st)  ((size_t)((st) >> 2) * 16384 + (size_t)((st) & 3) * 4096)
#define OFFV(ks)  ((size_t)((ks) >> 3) * 196608 + (size_t)(((ks) >> 2) & 1) * 16384 \
                   + (size_t)((ks) & 3) * 4096)

__global__ __launch_bounds__(512, 2) void lsa_main(
    const float* __restrict__ Qg, const float* __restrict__ Tg,
    const unsigned short* __restrict__ Kws, const unsigned short* __restrict__ Vws,
    float* __restrict__ Og)
{
    extern __shared__ char sm[];
    const int tid  = threadIdx.x;
    const int lane = tid & 63;
    const int w    = tid >> 6;
    const int hh   = lane >> 5;
    const int l31  = lane & 31;

    int id = blockIdx.x;
    int xcd = id & 7, jj = id >> 3;
    int batch = (jj >> 5) * 16 + xcd * 2 + ((jj >> 4) & 1);
    int qt = jj & 15;

    const char* kimg = (const char*)Kws + (size_t)batch * 1572864;
    const char* vimg = (const char*)Vws + (size_t)batch * 1572864;
    float* redm = (float*)(sm + REDOFF);
    float* redl = (float*)(sm + REDOFF + 2048);

    // ---- stage Q fp32 -> bf16 frag image in LDS (fused Q-prep) ----
    {
        const float scale2 = 1.4426950408889634f / Tg[0];   // log2(e)/temp
        const float* qp = Qg + ((size_t)batch * 1024 + (size_t)qt * 64) * 768;
        const int row = tid >> 3, c0 = tid & 7;
        const float* qrow = qp + (size_t)row * 768;
        #pragma unroll
        for (int j5 = 0; j5 < 24; ++j5) {
            int c4 = c0 + j5 * 8;                // f32x4 index; k = c4*4
            f32x4v q4 = *(const f32x4v*)(qrow + c4 * 4);
            int k   = c4 * 4;
            int k16 = k >> 4, k15 = k & 15;
            int hh2 = k15 >> 3, j0 = k15 & 7;
            int frag = k16 * 2 + (row >> 5);
            bf16x4 hq = { (__bf16)(q4[0] * scale2), (__bf16)(q4[1] * scale2),
                          (__bf16)(q4[2] * scale2), (__bf16)(q4[3] * scale2) };
            *(bf16x4*)(sm + QOFF + frag * 1024
                       + (hh2 * 32 + (row & 31)) * 16 + j0 * 2) = hq;
        }
    }
    __syncthreads();

    f32x16 acc[3][2];
    #pragma unroll
    for (int g3 = 0; g3 < 3; ++g3)
        #pragma unroll
        for (int qg = 0; qg < 2; ++qg)
            #pragma unroll
            for (int r = 0; r < 16; ++r) acc[g3][qg][r] = 0.0f;
    float m_st[2] = { -3e38f, -3e38f };
    float l_st[2] = { 0.0f, 0.0f };

    const char* kbase = kimg + (size_t)(w >> 1) * 196608 + (size_t)(w & 1) * 2048
                        + (size_t)lane * 16;
    size_t voff3[3];
    #pragma unroll
    for (int g3 = 0; g3 < 3; ++g3) {
        int dgi = w * 3 + g3;
        voff3[g3] = (size_t)(dgi >> 2) * 32768 + (size_t)(dgi & 3) * 1024
                    + (size_t)lane * 16;
    }
    const int diag_t2 = qt >> 3;
    const int wlo = (w < 4);

    #pragma unroll 1
    for (int t2 = 0; t2 < 2; ++t2) {
        // ========== QK^T: 48 steps x 4 MFMA, dbuf qf + ring-5 K ==========
        const char* kb = kbase + (size_t)t2 * 786432;
        f32x16 s[2][2];
        #pragma unroll
        for (int kk = 0; kk < 2; ++kk)
            #pragma unroll
            for (int qg = 0; qg < 2; ++qg)
                #pragma unroll
                for (int r = 0; r < 16; ++r) s[kk][qg][r] = 0.0f;

        bf16x8 kr0[5], kr1[5];
        #pragma unroll
        for (int p = 0; p < 5; ++p) {
            kr0[p] = *(const bf16x8*)(kb + OFFK(p));
            kr1[p] = *(const bf16x8*)(kb + OFFK(p) + 1024);
        }
        bf16x8 qf[2][2];
        qf[0][0] = *(const bf16x8*)(sm + QOFF + 0 + lane * 16);
        qf[0][1] = *(const bf16x8*)(sm + QOFF + 1024 + lane * 16);

        #pragma unroll
        for (int st = 0; st < 48; ++st) {
            const int cur = st & 1, nxt = cur ^ 1;
            if (st < 47) {
                qf[nxt][0] = *(const bf16x8*)(sm + QOFF + ((st + 1) * 2 + 0) * 1024 + lane * 16);
                qf[nxt][1] = *(const bf16x8*)(sm + QOFF + ((st + 1) * 2 + 1) * 1024 + lane * 16);
            }
            __builtin_amdgcn_s_setprio(1);
            s[0][0] = __builtin_amdgcn_mfma_f32_32x32x16_bf16(kr0[st % 5], qf[cur][0], s[0][0], 0, 0, 0);
            s[0][1] = __builtin_amdgcn_mfma_f32_32x32x16_bf16(kr0[st % 5], qf[cur][1], s[0][1], 0, 0, 0);
            s[1][0] = __builtin_amdgcn_mfma_f32_32x32x16_bf16(kr1[st % 5], qf[cur][0], s[1][0], 0, 0, 0);
            s[1][1] = __builtin_amdgcn_mfma_f32_32x32x16_bf16(kr1[st % 5], qf[cur][1], s[1][1], 0, 0, 0);
            __builtin_amdgcn_s_setprio(0);
            if (st < 43) {
                kr0[st % 5] = *(const bf16x8*)(kb + OFFK(st + 5));
                kr1[st % 5] = *(const bf16x8*)(kb + OFFK(st + 5) + 1024);
            }
        }

        // ---- V ring warm-up (lands under softmax) ----
        const char* vbt = vimg + (size_t)t2 * 786432;
        bf16x8 vrg[2][3];
        #pragma unroll
        for (int p = 0; p < 2; ++p)
            #pragma unroll
            for (int g3 = 0; g3 < 3; ++g3)
                vrg[p][g3] = *(const bf16x8*)(vbt + voff3[g3] + OFFV(p));

        // diagonal self-exclusion
        if (t2 == diag_t2) {
            #pragma unroll
            for (int kk = 0; kk < 2; ++kk)
                #pragma unroll
                for (int qg = 0; qg < 2; ++qg)
                    #pragma unroll
                    for (int r = 0; r < 16; ++r) {
                        int kvg = t2 * 512 + w * 64 + kk * 32 + (r & 3) + 8 * (r >> 2) + 4 * hh;
                        if (kvg == qt * 64 + qg * 32 + l31) s[kk][qg][r] = -3e38f;
                    }
        }

        // ================= online softmax =================
        #pragma unroll
        for (int qg = 0; qg < 2; ++qg) {
            float pm = s[0][qg][0];
            #pragma unroll
            for (int r = 1; r < 16; ++r) pm = fmaxf(pm, s[0][qg][r]);
            #pragma unroll
            for (int r = 0; r < 16; ++r) pm = fmaxf(pm, s[1][qg][r]);
            pm = fmaxf(pm, __shfl_xor(pm, 32, 64));
            if (hh == 0) redm[(qg * 32 + l31) * 8 + w] = pm;
        }
        LGKM0_BAR();                           // bar1
        float cf[2];
        #pragma unroll
        for (int qg = 0; qg < 2; ++qg) {
            const float* rp = redm + (qg * 32 + l31) * 8;
            f32x4v a = *(const f32x4v*)rp;
            f32x4v b = *(const f32x4v*)(rp + 4);
            float mn = fmaxf(fmaxf(fmaxf(a[0], a[1]), fmaxf(a[2], a[3])),
                             fmaxf(fmaxf(b[0], b[1]), fmaxf(b[2], b[3])));
            mn = fmaxf(mn, m_st[qg]);
            cf[qg] = __builtin_amdgcn_exp2f(m_st[qg] - mn);
            m_st[qg] = mn;
            float pl = 0.0f;
            #pragma unroll
            for (int kk = 0; kk < 2; ++kk)
                #pragma unroll
                for (int r = 0; r < 16; ++r) {
                    float e = __builtin_amdgcn_exp2f(s[kk][qg][r] - mn);
                    s[kk][qg][r] = e; pl += e;
                }
            pl += __shfl_xor(pl, 32, 64);
            l_st[qg] = l_st[qg] * cf[qg] + pl;
        }

        #define WRITE_P() do {                                                      \
            _Pragma("unroll")                                                       \
            for (int kk = 0; kk < 2; ++kk)                                          \
                _Pragma("unroll")                                                   \
                for (int g = 0; g < 4; ++g)                                         \
                    _Pragma("unroll")                                               \
                    for (int qg = 0; qg < 2; ++qg) {                                \
                        bf16x4 p4 = { (__bf16)s[kk][qg][4*g+0], (__bf16)s[kk][qg][4*g+1], \
                                      (__bf16)s[kk][qg][4*g+2], (__bf16)s[kk][qg][4*g+3] }; \
                        int bidx = (((w & 3) * 4 + kk * 2 + (g >> 1)) * 2 + qg);    \
                        *(bf16x4*)(sm + POFF + bidx * 1024                          \
                                   + ((g & 1) * 32 + l31) * 16 + hh * 8) = p4;      \
                    } } while (0)

        if (wlo) WRITE_P();                    // waves 0-3: kv 0..255

        // acc rescale AFTER P writes (overlaps ds_write/barrier)
        #pragma unroll
        for (int g3 = 0; g3 < 3; ++g3)
            #pragma unroll
            for (int qg = 0; qg < 2; ++qg)
                #pragma unroll
                for (int r = 0; r < 16; ++r) acc[g3][qg][r] *= cf[qg];

        LGKM0_BAR();                           // bar2: P-A ready

        // ============ PV sub-phase A: lk 0..15, dbuf pa + ring-2 V ============
        bf16x8 pa[2][2];
        pa[0][0] = *(const bf16x8*)(sm + POFF + 0 + lane * 16);
        pa[0][1] = *(const bf16x8*)(sm + POFF + 1024 + lane * 16);
        #pragma unroll
        for (int lk = 0; lk < 16; ++lk) {
            const int cur = lk & 1, nxt = cur ^ 1;
            if (lk < 15) {
                pa[nxt][0] = *(const bf16x8*)(sm + POFF + ((lk + 1) * 2 + 0) * 1024 + lane * 16);
                pa[nxt][1] = *(const bf16x8*)(sm + POFF + ((lk + 1) * 2 + 1) * 1024 + lane * 16);
            }
            __builtin_amdgcn_s_setprio(1);
            #pragma unroll
            for (int g3 = 0; g3 < 3; ++g3) {
                acc[g3][0] = __builtin_amdgcn_mfma_f32_32x32x16_bf16(vrg[lk & 1][g3], pa[cur][0], acc[g3][0], 0, 0, 0);
                acc[g3][1] = __builtin_amdgcn_mfma_f32_32x32x16_bf16(vrg[lk & 1][g3], pa[cur][1], acc[g3][1], 0, 0, 0);
            }
            __builtin_amdgcn_s_setprio(0);
            #pragma unroll
            for (int g3 = 0; g3 < 3; ++g3)
                vrg[lk & 1][g3] = *(const bf16x8*)(vbt + voff3[g3] + OFFV(lk + 2));
        }
        LGKM0_BAR();                           // bar3: P-A reads done
        if (!wlo) WRITE_P();                   // waves 4-7: kv 256..511
        LGKM0_BAR();                           // bar4: P-B ready

        // ================= PV sub-phase B: lk 16..31 =================
        pa[0][0] = *(const bf16x8*)(sm + POFF + 0 + lane * 16);
        pa[0][1] = *(const bf16x8*)(sm + POFF + 1024 + lane * 16);
        #pragma unroll
        for (int lk = 16; lk < 32; ++lk) {
            const int cur = lk & 1, nxt = cur ^ 1;
            if (lk < 31) {
                pa[nxt][0] = *(const bf16x8*)(sm + POFF + ((lk - 15) * 2 + 0) * 1024 + lane * 16);
                pa[nxt][1] = *(const bf16x8*)(sm + POFF + ((lk - 15) * 2 + 1) * 1024 + lane * 16);
            }
            __builtin_amdgcn_s_setprio(1);
            #pragma unroll
            for (int g3 = 0; g3 < 3; ++g3) {
                acc[g3][0] = __builtin_amdgcn_mfma_f32_32x32x16_bf16(vrg[lk & 1][g3], pa[cur][0], acc[g3][0], 0, 0, 0);
                acc[g3][1] = __builtin_amdgcn_mfma_f32_32x32x16_bf16(vrg[lk & 1][g3], pa[cur][1], acc[g3][1], 0, 0, 0);
            }
            __builtin_amdgcn_s_setprio(0);
            if (lk < 30) {
                #pragma unroll
                for (int g3 = 0; g3 < 3; ++g3)
                    vrg[lk & 1][g3] = *(const bf16x8*)(vbt + voff3[g3] + OFFV(lk + 2));
            }
        }
        #undef WRITE_P
    }

    // ================= epilogue =================
    #pragma unroll
    for (int qg = 0; qg < 2; ++qg)
        if (hh == 0) redl[(qg * 32 + l31) * 8 + w] = l_st[qg];
    __syncthreads();
    float rinv[2];
    #pragma unroll
    for (int qg = 0; qg < 2; ++qg) {
        const float* rp = redl + (qg * 32 + l31) * 8;
        f32x4v a = *(const f32x4v*)rp;
        f32x4v b = *(const f32x4v*)(rp + 4);
        rinv[qg] = 1.0f / (a[0] + a[1] + a[2] + a[3] + b[0] + b[1] + b[2] + b[3]);
    }

    char* obt = sm + QOFF;                     // reuse Q space: [64 q][256 d] f32
    const size_t orow = (size_t)batch * 1024 + (size_t)qt * 64;
    const int q2 = tid >> 3, c8 = tid & 7;

    #pragma unroll
    for (int g3 = 0; g3 < 3; ++g3) {
        __syncthreads();
        #pragma unroll
        for (int qg = 0; qg < 2; ++qg) {
            int q = qg * 32 + l31;
            int qx = (q & 15) << 4;
            #pragma unroll
            for (int g = 0; g < 4; ++g) {
                f32x4v o4 = { acc[g3][qg][4 * g + 0] * rinv[qg],
                              acc[g3][qg][4 * g + 1] * rinv[qg],
                              acc[g3][qg][4 * g + 2] * rinv[qg],
                              acc[g3][qg][4 * g + 3] * rinv[qg] };
                int dloc = w * 32 + 8 * g + 4 * hh;
                *(f32x4v*)(obt + q * 1024 + ((dloc * 4) ^ qx)) = o4;
            }
        }
        __syncthreads();
        #pragma unroll
        for (int i = 0; i < 8; ++i) {
            int db = c8 * 128 + i * 16;
            f32x4v o = *(const f32x4v*)(obt + q2 * 1024 + (db ^ ((q2 & 15) << 4)));
            int dg = c8 * 96 + g3 * 32 + i * 4;
            *(f32x4v*)(Og + (orow + q2) * 768 + dg) = o;
        }
    }
}

// ============================ fallback (round-2 kernel) ============================
__device__ __forceinline__ void fb_stage_load(f32x4v (&vr)[2][4], const float* __restrict__ Vg,
                                              size_t kvbase, int srg, int scg, int ch) {
    #pragma unroll
    for (int i2 = 0; i2 < 2; ++i2) {
        const float* vp = Vg + kvbase + (size_t)(srg * 4) * 768 + ch * 128 + (scg + i2 * 16) * 4;
        #pragma unroll
        for (int rr = 0; rr < 4; ++rr)
            vr[i2][rr] = *(const f32x4v*)(vp + (size_t)rr * 768);
    }
}
__device__ __forceinline__ void fb_stage_write(const f32x4v (&vr)[2][4], char* Vb, int srg, int scg) {
    #pragma unroll
    for (int i2 = 0; i2 < 2; ++i2) {
        int cg = scg + i2 * 16;
        #pragma unroll
        for (int q4 = 0; q4 < 4; ++q4) {
            int drow = cg * 4 + q4;
            bf16x4 hv = { (__bf16)vr[i2][0][q4], (__bf16)vr[i2][1][q4],
                          (__bf16)vr[i2][2][q4], (__bf16)vr[i2][3][q4] };
            *(bf16x4*)(Vb + drow * 256 + ((srg * 8) ^ ((drow & 15) << 4))) = hv;
        }
    }
}
#define FB_OFF_V  98304
#define FB_OFF_P  131072
#define FB_OFF_RM 147456
#define FB_OFF_RL 148480
#define FB_LDS    149504
__global__ __launch_bounds__(512) void lsa_fb(
    const float* __restrict__ Qg, const float* __restrict__ Kg,
    const float* __restrict__ Vg, const float* __restrict__ Tg,
    float* __restrict__ Og)
{
    extern __shared__ char smem[];
    char*  Qb    = smem;
    char*  Vb    = smem + FB_OFF_V;
    char*  Pb    = smem + FB_OFF_P;
    float* red_m = (float*)(smem + FB_OFF_RM);
    float* red_l = (float*)(smem + FB_OFF_RL);
    const int tid  = threadIdx.x;
    const int lane = tid & 63;
    const int w    = tid >> 6;
    const int mr   = w & 1;
    const int nc   = w >> 1;
    const int half = lane >> 5;
    const int l31  = lane & 31;
    int id = blockIdx.x, xcd = id & 7, jj = id >> 3;
    int batch = (jj >> 5) * 16 + xcd * 2 + ((jj >> 4) & 1);
    int qt = jj & 15;
    const float scale2 = 1.4426950408889634f / Tg[0];
    {
        const float* qp   = Qg + ((size_t)batch * 1024 + (size_t)qt * 64) * 768;
        int   row   = tid >> 3, c0 = tid & 7;
        const float* qrow = qp + (size_t)row * 768;
        char* qdst  = Qb + row * 1536;
        int   rx    = (row & 15) << 4;
        #pragma unroll
        for (int j = 0; j < 24; ++j) {
            int c4 = c0 + j * 8;
            f32x4v q4 = *(const f32x4v*)(qrow + c4 * 4);
            bf16x4 hq = { (__bf16)(q4[0] * scale2), (__bf16)(q4[1] * scale2),
                          (__bf16)(q4[2] * scale2), (__bf16)(q4[3] * scale2) };
            *(bf16x4*)(qdst + ((c4 * 8) ^ rx)) = hq;
        }
    }
    __syncthreads();
    f32x16 acc[6];
    #pragma unroll
    for (int ch = 0; ch < 6; ++ch)
        #pragma unroll
        for (int r = 0; r < 16; ++r) acc[ch][r] = 0.0f;
    float m_st = -3e38f, l_st = 0.0f;
    const int  qrow_g = mr * 32 + l31;
    const int  qglob  = qt * 64 + qrow_g;
    char*      qfbase = Qb + qrow_g * 1536;
    const int  qx     = (qrow_g & 15) << 4;
    char*      pfbase = Pb + qrow_g * 256;
    const int  vrow   = nc * 32 + l31;
    char*      vfbase = Vb + vrow * 256;
    const int  vx     = (vrow & 15) << 4;
    const int  diag_tile = qt >> 1;
    const int  srg = tid & 31, scg = tid >> 5;
    #pragma unroll 1
    for (int t = 0; t < 8; ++t) {
        const size_t kvbase = ((size_t)batch * 1024 + (size_t)t * 128) * 768;
        f32x16 s;
        #pragma unroll
        for (int r = 0; r < 16; ++r) s[r] = 0.0f;
        const float* kptr = Kg + kvbase + (size_t)(nc * 32 + l31) * 768 + 8 * half;
        #pragma unroll
        for (int ch = 0; ch < 6; ++ch) {
            #pragma unroll
            for (int ks = 0; ks < 8; ++ks) {
                f32x4v k0 = *(const f32x4v*)(kptr + ch * 128 + ks * 16);
                f32x4v k1 = *(const f32x4v*)(kptr + ch * 128 + ks * 16 + 4);
                bf16x8 kf = { (__bf16)k0[0], (__bf16)k0[1], (__bf16)k0[2], (__bf16)k0[3],
                              (__bf16)k1[0], (__bf16)k1[1], (__bf16)k1[2], (__bf16)k1[3] };
                bf16x8 qf = *(const bf16x8*)(qfbase + ((ch * 256 + ks * 32 + half * 16) ^ qx));
                s = __builtin_amdgcn_mfma_f32_32x32x16_bf16(kf, qf, s, 0, 0, 0);
            }
        }
        if (t == diag_tile) {
            #pragma unroll
            for (int r = 0; r < 16; ++r) {
                int kvg = t * 128 + nc * 32 + (r & 3) + 8 * (r >> 2) + 4 * half;
                if (kvg == qglob) s[r] = -3e38f;
            }
        }
        f32x4v vr[2][4];
        fb_stage_load(vr, Vg, kvbase, srg, scg, 0);
        float pm = s[0];
        #pragma unroll
        for (int r = 1; r < 16; ++r) pm = fmaxf(pm, s[r]);
        pm = fmaxf(pm, __shfl_xor(pm, 32, 64));
        if (half == 0) red_m[qrow_g * 4 + nc] = pm;
        __syncthreads();
        f32x4v m4 = *(const f32x4v*)(red_m + qrow_g * 4);
        float mnew = fmaxf(fmaxf(m4[0], m4[1]), fmaxf(m4[2], m4[3]));
        mnew = fmaxf(mnew, m_st);
        float cf = __builtin_amdgcn_exp2f(m_st - mnew);
        m_st = mnew;
        float pl = 0.0f;
        #pragma unroll
        for (int r = 0; r < 16; ++r) {
            float e = __builtin_amdgcn_exp2f(s[r] - mnew);
            s[r] = e; pl += e;
        }
        pl += __shfl_xor(pl, 32, 64);
        l_st = l_st * cf + pl;
        #pragma unroll
        for (int ch = 0; ch < 6; ++ch)
            #pragma unroll
            for (int r = 0; r < 16; ++r) acc[ch][r] *= cf;
        #pragma unroll
        for (int g = 0; g < 4; ++g) {
            bf16x4 hp = { (__bf16)s[4*g+0], (__bf16)s[4*g+1],
                          (__bf16)s[4*g+2], (__bf16)s[4*g+3] };
            *(bf16x4*)(pfbase + ((nc * 64 + g * 16 + half * 8) ^ qx)) = hp;
        }
        fb_stage_write(vr, Vb, srg, scg);
        __syncthreads();
        bf16x8 pa[8];
        #pragma unroll
        for (int ks = 0; ks < 8; ++ks)
            pa[ks] = *(const bf16x8*)(pfbase + ((ks * 32 + half * 16) ^ qx));
        #pragma unroll
        for (int ch = 0; ch < 6; ++ch) {
            if (ch < 5) fb_stage_load(vr, Vg, kvbase, srg, scg, ch + 1);
            #pragma unroll
            for (int ks = 0; ks < 8; ++ks) {
                bf16x8 vf = *(const bf16x8*)(vfbase + ((ks * 32 + half * 16) ^ vx));
                acc[ch] = __builtin_amdgcn_mfma_f32_32x32x16_bf16(vf, pa[ks], acc[ch], 0, 0, 0);
            }
            if (ch < 5) {
                __syncthreads();
                fb_stage_write(vr, Vb, srg, scg);
                __syncthreads();
            }
        }
    }
    if (half == 0) red_l[qrow_g * 4 + nc] = l_st;
    __syncthreads();
    f32x4v l4 = *(const f32x4v*)(red_l + qrow_g * 4);
    float rinv = 1.0f / (l4[0] + l4[1] + l4[2] + l4[3]);
    float* op = Og + ((size_t)batch * 1024 + (size_t)qglob) * 768;
    #pragma unroll
    for (int ch = 0; ch < 6; ++ch)
        #pragma unroll
        for (int g = 0; g < 4; ++g) {
            f32x4v o4 = { acc[ch][4*g+0] * rinv, acc[ch][4*g+1] * rinv,
                          acc[ch][4*g+2] * rinv, acc[ch][4*g+3] * rinv };
            *(f32x4v*)(op + ch * 128 + nc * 32 + g * 8 + half * 4) = o4;
        }
}

extern "C" void kernel_launch(void* const* d_in, const int* in_sizes, int n_in,
                              void* d_out, int out_size, void* d_ws, size_t ws_size,
                              hipStream_t stream) {
    (void)in_sizes; (void)n_in; (void)out_size;
    const float* Q = (const float*)d_in[0];
    const float* K = (const float*)d_in[1];
    const float* V = (const float*)d_in[2];
    const float* T = (const float*)d_in[3];
    float* O = (float*)d_out;
    if (ws_size >= WS_NEEDED) {
        unsigned short* Kws = (unsigned short*)((char*)d_ws + WS_K);
        unsigned short* Vws = (unsigned short*)((char*)d_ws + WS_V);
        prep_kv<<<dim3(1024), dim3(512), 0, stream>>>(K, V, Kws, Vws);
        lsa_main<<<dim3(1024), dim3(512), LDS_MAIN, stream>>>(Q, T, Kws, Vws, O);
    } else {
        lsa_fb<<<dim3(1024), dim3(512), FB_LDS, stream>>>(Q, K, V, T, O);
    }
}